// Round 7
// baseline (399.062 us; speedup 1.0000x reference)
//
#include <hip/hip_runtime.h>
#include <math.h>

#define B_ 2
#define L_ 1024
#define DM_ 1024
#define STATE_ 16
#define CONV_ 4
#define DTR_ 8
#define INNER_ 2048
#define M_ (B_*L_)        /* 2048 rows (b,l) */
#define MD_ (B_*INNER_)   /* 4096 rows (b,c) */
#define NFFT_ 513
#define NFP_ 1088         /* 2*513=1026 padded to 17*64 */
#define NCH_ 32
#define CHL_ 32
#define SK_ 16            /* x_proj split-K factor */
#define KSL_ (2048/SK_)   /* 128 */

typedef unsigned short u16;
typedef __attribute__((ext_vector_type(8))) short short8;
typedef __attribute__((ext_vector_type(8))) __bf16 bf16x8;
typedef __attribute__((ext_vector_type(4))) float f32x4;

__device__ __forceinline__ float frcp_(float x) { return __builtin_amdgcn_rcpf(x); }
__device__ __forceinline__ float fexp_(float x) { return __expf(x); }
__device__ __forceinline__ float fsigm_(float x) { return frcp_(1.f + __expf(-x)); }
__device__ __forceinline__ float fsilu_(float x) { return x * frcp_(1.f + __expf(-x)); }
__device__ __forceinline__ float fsoftplus_(float v) {
  return (v > 20.f) ? v : __logf(1.f + __expf(v));
}
__device__ __forceinline__ u16 f2bf(float f) {
  union { float f; unsigned u; } v; v.f = f;
  unsigned r = v.u + 0x7fffu + ((v.u >> 16) & 1u);
  return (u16)(r >> 16);
}
__device__ __forceinline__ float bf2f(u16 h) {
  union { unsigned u; float f; } v; v.u = ((unsigned)h) << 16;
  return v.f;
}
__device__ __forceinline__ void gload16(const void* g, void* l) {
  __builtin_amdgcn_global_load_lds(
      (const __attribute__((address_space(1))) unsigned*)g,
      (__attribute__((address_space(3))) unsigned*)l, 16, 0, 0);
}
__device__ __forceinline__ f32x4 mfma_bf16(short8 a, short8 b, f32x4 c) {
  return __builtin_amdgcn_mfma_f32_16x16x32_bf16(
      __builtin_bit_cast(bf16x8, a), __builtin_bit_cast(bf16x8, b), c, 0, 0, 0);
}

// ---------------- fp32 -> bf16 conversion (x + in_w only) -------------------
#define CVT2_N0 2097152
#define CVT2_NT 6291456
__global__ __launch_bounds__(256) void cvt2_k(
    const float* __restrict__ s0, const float* __restrict__ s1,
    u16* __restrict__ out)
{
  int i = (blockIdx.x*256 + threadIdx.x) * 4;
  const float* src; int off;
  if (i < CVT2_N0) { src = s0; off = 0; }
  else             { src = s1; off = CVT2_N0; }
  float4 v = *(const float4*)(src + (i - off));
  ushort4 o;
  o.x = f2bf(v.x); o.y = f2bf(v.y); o.z = f2bf(v.z); o.w = f2bf(v.w);
  *(ushort4*)(out + i) = o;
}

// ---------------- aux bodies ------------------------------------------------
// 16 contiguous floats per thread -> bf16
__device__ __forceinline__ void cvt16_body(int eb, int nthr, int t,
    const float* __restrict__ src, u16* __restrict__ dst)
{
  int i = (eb*nthr + t)*16;
  #pragma unroll
  for (int q = 0; q < 4; q++) {
    float4 v = *(const float4*)(src + i + q*4);
    ushort4 o;
    o.x = f2bf(v.x); o.y = f2bf(v.y); o.z = f2bf(v.z); o.w = f2bf(v.w);
    *(ushort4*)(dst + i + q*4) = o;
  }
}

// depthwise causal conv(4) + silu, 8 l per thread; ALSO emits x_inner^T bf16
// (pre-conv values) coalesced into xt[b*2048+c][l] for the DFT GEMM.
__device__ __forceinline__ void conv_xt_body(int idx, const float* __restrict__ xz,
    const float* __restrict__ cw, const float* __restrict__ cb,
    float* __restrict__ xc, u16* __restrict__ xt)
{
  int c = idx & (INNER_-1);
  int g = idx >> 11;                        // 0..255
  int b = g >> 7;
  int lb = (g & 127) * 8;
  float w0=cw[c*4+0], w1=cw[c*4+1], w2=cw[c*4+2], w3=cw[c*4+3];
  float bias = cb[c];
  float v[11];
  #pragma unroll
  for (int j = 0; j < 11; j++) {
    int l = lb - 3 + j;
    v[j] = (l >= 0) ? xz[((size_t)((b << 10) + l))*4096 + c] : 0.f;
  }
  union { u16 a[8]; short8 v8; } tu;
  #pragma unroll
  for (int j = 0; j < 8; j++) tu.a[j] = f2bf(v[j+3]);
  *(short8*)&xt[(((size_t)(b*INNER_ + c)) << 10) + lb] = tu.v8;
  #pragma unroll
  for (int j = 0; j < 8; j++) {
    float s = bias + w0*v[j] + w1*v[j+1] + w2*v[j+2] + w3*v[j+3];
    xc[((size_t)((b << 10) + lb + j))*INNER_ + c] = fsilu_(s);
  }
}

// DFT matrix (bf16, K-contiguous): W[col*1024 + l], col < NFP_
__device__ __forceinline__ void genWdft_body(int idx, u16* __restrict__ W)
{
  int l = idx & (L_-1);
  int col = idx >> 10;
  float v = 0.f;
  int f = col >> 1;
  if (f < NFFT_) {
    int ph = (l*f) & (L_-1);
    float th = (float)ph * (6.283185307179586f / (float)L_);
    v = (col & 1) ? -__sinf(th) : __cosf(th);
  }
  W[idx] = f2bf(v);
}

// inverse-DFT matrix: W[l*NFP_ + r], l < 1024, r < NFP_
__device__ __forceinline__ void genWinv_body(int idx, u16* __restrict__ W)
{
  int r = idx % NFP_;
  int l = idx / NFP_;
  int f = r >> 1;
  float v = 0.f;
  if (f < NFFT_) {
    bool edge = (f == 0) || (f == 512);
    float sc = (edge ? 1.f : 2.f) / (float)L_;
    int ph = (f*l) & (L_-1);
    float th = (float)ph * (6.283185307179586f / (float)L_);
    if (r & 1) v = edge ? 0.f : -sc*__sinf(th);
    else       v = sc*__cosf(th);
  }
  W[idx] = f2bf(v);
}

// x_proj split-K slice: part[sk][m][40] = xconv[m, sk*KSL_:+KSL_] @ W^T
// W reads use wave-UNIFORM addresses (no lane dependence) -> compiler emits
// scalar s_load_dwordx4 (K$ path); no LDS, no __syncthreads. This removes
// the 1280 ds_read_b128/thread LDS-pipe tail the LDS-staged version had.
__device__ __forceinline__ void xproj_body(int eb,
    const float* __restrict__ xconv, const float* __restrict__ W,
    float* __restrict__ part)
{
  const int sk = eb & (SK_-1), mt = eb / SK_;
  const int k0 = sk*KSL_;
  const int m = mt*256 + threadIdx.x;
  const float* arow = xconv + (size_t)m*2048 + k0;
  const float* wrow = W + k0;
  float acc[40];
  #pragma unroll
  for (int j=0;j<40;j++) acc[j]=0.f;
  for (int k = 0; k < KSL_; k += 4) {
    float4 a = *(const float4*)(arow + k);
    #pragma unroll
    for (int j = 0; j < 40; j++) {
      float4 b = *(const float4*)(wrow + (size_t)j*2048 + k);  // uniform -> s_load
      acc[j] += a.x*b.x + a.y*b.y + a.z*b.z + a.w*b.w;
    }
  }
  float* o = part + ((size_t)sk*M_ + m)*40;
  #pragma unroll
  for (int j = 0; j < 10; j++)
    *(float4*)(o + j*4) = make_float4(acc[j*4], acc[j*4+1], acc[j*4+2], acc[j*4+3]);
}

// x_dbc reduce over SK_ partials; i < M_*40
__device__ __forceinline__ void xpred_body(int i, const float* __restrict__ part,
                                           float* __restrict__ xdbc)
{
  float s = 0.f;
  #pragma unroll
  for (int sk = 0; sk < SK_; sk++) s += part[(size_t)sk*81920 + i];
  xdbc[i] = s;
}

// ---------------- standalone aux launch: conv+xt, genWinv, cvt out_w --------
__global__ __launch_bounds__(256) void aux2_k(
    const float* __restrict__ xz, const float* __restrict__ cw,
    const float* __restrict__ cb, float* __restrict__ xc,
    u16* __restrict__ xt, u16* __restrict__ Winv,
    const float* __restrict__ ows, u16* __restrict__ owd)
{
  int eb = blockIdx.x;
  if (eb < 2048)      conv_xt_body(eb*256 + threadIdx.x, xz, cw, cb, xc, xt);
  else if (eb < 6400) genWinv_body((eb - 2048)*256 + threadIdx.x, Winv);
  else                cvt16_body(eb - 6400, 256, threadIdx.x, ows, owd);
}

// ---------------- bf16 MFMA GEMM (templated tile, double-buffered) ----------
// C[m,n] = sum_k A[m,k0+k]*Bt[n,k0+k], k < K (per-split), row stride ldk.
// KS splits along K; split ks = bid/(gx*gy), k0 = ks*K.
// AUX blocks beyond KS*gx*gy: 1 = genWdft + cvt16 fus_w; 3 = xproj;
// 4 = xpred. All independent of this launch's GEMM + disjoint memory.
// EPI: 0 plain f32; 3 spectral filter (bf16); 6 inv-DFT via LDS-transpose
//      (coalesced 16B stores into ycat[:,2048:]); 7 f32 split-K partial;
//      8 bf16 split-K partial.
template<int TM, int TN, int EPI, int YCH, int AUX, int KS>
__global__ __launch_bounds__((TM/64)*(TN/32)*64) void mgemm_k(
    const u16* __restrict__ Ab, const u16* __restrict__ Bb,
    void* __restrict__ Cout, int K, int ldc,
    const float* __restrict__ aux0, u16* __restrict__ aux1,
    const float* __restrict__ aux2, const float* __restrict__ aux3,
    int gx, int gy,
    const float* __restrict__ ga, const float* __restrict__ gb,
    float* __restrict__ go, u16* __restrict__ gw,
    int ldk, const float* __restrict__ cvs, u16* __restrict__ cvd)
{
  constexpr int WN   = TN/32;
  constexpr int NW   = (TM/64)*WN;
  constexpr int NTHR = NW*64;
  __shared__ __align__(16) u16 As[2][TM*64];
  __shared__ __align__(16) u16 Bs[2][TN*64];
  const int t = threadIdx.x;
  const int nwg = gx * gy;

  if constexpr (AUX != 0) {
    int eb = (int)blockIdx.x - nwg*KS;
    if (eb >= 0) {
      if constexpr (AUX == 1) {              // genWdft (2176) + cvt fus_w (1024)
        if (eb < 2176) genWdft_body(eb*NTHR + t, gw);
        else           cvt16_body(eb - 2176, NTHR, t, cvs, cvd);
      } else if constexpr (AUX == 3) {       // xproj (SK_*8 = 128 blks)
        xproj_body(eb, ga, gb, go);
      } else {                               // 4: xpred (320 blks)
        xpred_body(eb*256 + t, ga, go);
      }
      return;
    }
  }

  const int lane = t & 63;
  const int w = t >> 6;
  const int wm = w / WN, wn = w % WN;

  // split-K id + XCD-chunked bijective remap (nwg % 8 == 0 everywhere)
  int bid = blockIdx.x;
  int ks = 0;
  if constexpr (KS > 1) { ks = bid / nwg; bid -= ks*nwg; }
  const int k0 = ks * K;
  const int lid = (bid & 7) * (nwg >> 3) + (bid >> 3);
  int bx, by;
  if (YCH) { by = lid / gx; bx = lid - by*gx; }
  else     { bx = lid / gy; by = lid - bx*gy; }
  const int M0 = by * TM, N0 = bx * TN;

  f32x4 acc[4][2] = {};

  auto stage = [&](int buf, int kk0) {
    #pragma unroll
    for (int q = 0; q < TM*8/NTHR; q++) {
      int u = q*NTHR + t;
      int row = u >> 3, gpr = u & 7;
      int grp = gpr ^ (row & 7);        // XOR swizzle
      gload16(Ab + (size_t)(M0+row)*ldk + k0 + kk0 + grp*8, &As[buf][u*8]);
    }
    #pragma unroll
    for (int q = 0; q < TN*8/NTHR; q++) {
      int u = q*NTHR + t;
      int row = u >> 3, gpr = u & 7;
      int grp = gpr ^ (row & 7);
      gload16(Bb + (size_t)(N0+row)*ldk + k0 + kk0 + grp*8, &Bs[buf][u*8]);
    }
  };

  stage(0, 0);
  const int nk = K >> 6;
  for (int kst = 0; kst < nk; kst++) {
    const int buf = kst & 1;
    __syncthreads();                    // drain stage(buf); protect buf^1 overwrite
    if (kst + 1 < nk) stage(buf ^ 1, (kst + 1) << 6);
    const u16* Asb = As[buf];
    const u16* Bsb = Bs[buf];
    #pragma unroll
    for (int kk = 0; kk < 2; kk++) {
      const int quad = lane >> 4;
      const int grp = kk*4 + quad;
      short8 af[4], bfr[2];
      #pragma unroll
      for (int i = 0; i < 4; i++) {
        int row = wm*64 + i*16 + (lane & 15);
        af[i] = *(const short8*)&Asb[(row*8 + (grp ^ (row & 7)))*8];
      }
      #pragma unroll
      for (int j = 0; j < 2; j++) {
        int row = wn*32 + j*16 + (lane & 15);
        bfr[j] = *(const short8*)&Bsb[(row*8 + (grp ^ (row & 7)))*8];
      }
      #pragma unroll
      for (int i = 0; i < 4; i++)
        #pragma unroll
        for (int j = 0; j < 2; j++)
          acc[i][j] = mfma_bf16(af[i], bfr[j], acc[i][j]);
    }
  }

  if constexpr (EPI == 6) {
    // LDS-transpose epilogue: tile [c_loc 128][l_loc 64] -> coalesced 16B
    // stores into ycat[(b,l) row][2048 + c]. Pad 66 breaks bank aliasing.
    u16* T = (u16*)&As[0][0];           // 128*66*2 = 16.9KB <= 32KB As
    __syncthreads();                    // all waves done reading As
    #pragma unroll
    for (int i = 0; i < 4; i++) {
      int cb = wm*64 + i*16 + (lane >> 4)*4;
      #pragma unroll
      for (int j = 0; j < 2; j++) {
        int ll = wn*32 + j*16 + (lane & 15);
        #pragma unroll
        for (int r = 0; r < 4; r++)
          T[(cb + r)*66 + ll] = f2bf(acc[i][j][r]);
      }
    }
    __syncthreads();
    const int b2 = M0 >> 11, c0 = M0 & (INNER_-1);
    u16* yc = (u16*)Cout;
    #pragma unroll
    for (int q = 0; q < (TM*TN/8)/NTHR; q++) {
      int task = q*NTHR + t;
      int cg = task & 15, ll = task >> 4;
      union { u16 a[8]; short8 v8; } tu;
      #pragma unroll
      for (int e = 0; e < 8; e++) tu.a[e] = T[(cg*8 + e)*66 + ll];
      *(short8*)&yc[((size_t)((b2 << 10) + N0 + ll) << 12) + 2048 + c0 + cg*8] = tu.v8;
    }
  } else {
    // C/D layout: col = lane&15, row = (lane>>4)*4 + r
    #pragma unroll
    for (int i = 0; i < 4; i++) {
      int mbase = M0 + wm*64 + i*16 + (lane >> 4)*4;
      #pragma unroll
      for (int j = 0; j < 2; j++) {
        int n = N0 + wn*32 + j*16 + (lane & 15);
        #pragma unroll
        for (int r = 0; r < 4; r++) {
          int m = mbase + r;
          float v = acc[i][j][r];
          if (EPI == 0) {
            ((float*)Cout)[(size_t)m*ldc + n] = v;
          } else if (EPI == 3) {        // spectral filter, complex pair via shfl
            float pv = __shfl_xor(v, 1, 64);
            int f = n >> 1;
            float outv = 0.f;
            if (f < NFFT_) {
              int c = m & (INNER_-1);
              float d  = fexp_(-aux2[c] * (float)f * (1.f/512.f));
              float wr = aux0[c*NFFT_+f]*d, wi = aux3[c*NFFT_+f]*d;
              float a = (n & 1) ? pv : v;
              float b = (n & 1) ? v : pv;
              outv = (n & 1) ? (a*wi + b*wr) : (a*wr - b*wi);
            }
            ((u16*)Cout)[(size_t)m*ldc + n] = f2bf(outv);
          } else if (EPI == 7) {        // f32 split-K partial
            float* P = (float*)Cout + (size_t)ks * ((size_t)gy*TM*ldc);
            P[(size_t)m*ldc + n] = v;
          } else {                      // 8: bf16 split-K partial
            u16* P = (u16*)Cout + (size_t)ks * ((size_t)gy*TM*ldc);
            P[(size_t)m*ldc + n] = f2bf(v);
          }
        }
      }
    }
  }
}

// ---------------- fusion combine: gate epilogue over bf16 partials ----------
__global__ __launch_bounds__(256) void combine_gate_k(
    const u16* __restrict__ P, const float* __restrict__ fus_b,
    const u16* __restrict__ ycat, const float* __restrict__ xz,
    u16* __restrict__ ycomb)
{
  int i4 = (blockIdx.x*256 + threadIdx.x)*4;   // m*2048 + n
  int m = i4 >> 11, n = i4 & 2047;
  ushort4 p0 = *(const ushort4*)(P + i4);
  ushort4 p1 = *(const ushort4*)(P + 4194304 + i4);
  ushort4 ysv = *(const ushort4*)(ycat + (size_t)m*4096 + n);
  ushort4 ypv = *(const ushort4*)(ycat + (size_t)m*4096 + 2048 + n);
  float4 zv = *(const float4*)(xz + (size_t)m*4096 + 2048 + n);
  float4 fb = *(const float4*)(fus_b + n);
  float pp[4] = {bf2f(p0.x)+bf2f(p1.x), bf2f(p0.y)+bf2f(p1.y),
                 bf2f(p0.z)+bf2f(p1.z), bf2f(p0.w)+bf2f(p1.w)};
  float zz[4] = {zv.x, zv.y, zv.z, zv.w};
  float bb[4] = {fb.x, fb.y, fb.z, fb.w};
  u16 ys[4] = {ysv.x, ysv.y, ysv.z, ysv.w};
  u16 yp[4] = {ypv.x, ypv.y, ypv.z, ypv.w};
  ushort4 o;
  u16* op = (u16*)&o;
  #pragma unroll
  for (int j = 0; j < 4; j++) {
    float g = fsigm_(pp[j] + bb[j]);
    op[j] = f2bf((g*bf2f(ys[j]) + (1.f-g)*bf2f(yp[j]))*fsilu_(zz[j]));
  }
  *(ushort4*)(ycomb + i4) = o;
}

// ---------------- SSM chunked scan (prefetched) ----------------
__global__ __launch_bounds__(256) void scan1_k(
    const float* __restrict__ xdbc, const float* __restrict__ xconv,
    const float* __restrict__ A_log, const float* __restrict__ dtw,
    const float* __restrict__ dtb, float* __restrict__ Pq)
{
  int idx = blockIdx.x*256 + threadIdx.x;   // (b*NCH+ch)*INNER + e
  int e  = idx & (INNER_-1);
  int bc = idx >> 11;
  int ch = bc & (NCH_-1);
  int b  = bc >> 5;
  float A[STATE_];
  #pragma unroll
  for (int s=0;s<STATE_;s++) A[s] = -fexp_(A_log[e*STATE_+s]);
  float w[DTR_];
  #pragma unroll
  for (int r=0;r<DTR_;r++) w[r] = dtw[e*DTR_+r];
  float bias = dtb[e];
  float h[STATE_] = {};
  float sdt = 0.f;
  int mbase = b*L_ + ch*CHL_;
  float dtx[DTR_], Bv[STATE_], xcv;
  {
    const float* row = xdbc + (size_t)mbase*40;
    #pragma unroll
    for (int r=0;r<DTR_;r++) dtx[r] = row[r];
    #pragma unroll
    for (int s=0;s<STATE_;s++) Bv[s] = row[8+s];
    xcv = xconv[(size_t)mbase*INNER_ + e];
  }
  for (int l=0;l<CHL_;l++) {
    float ndtx[DTR_], nBv[STATE_], nxcv = 0.f;
    if (l+1 < CHL_) {
      const float* nrow = xdbc + (size_t)(mbase+l+1)*40;
      #pragma unroll
      for (int r=0;r<DTR_;r++) ndtx[r] = nrow[r];
      #pragma unroll
      for (int s=0;s<STATE_;s++) nBv[s] = nrow[8+s];
      nxcv = xconv[(size_t)(mbase+l+1)*INNER_ + e];
    } else {
      #pragma unroll
      for (int r=0;r<DTR_;r++) ndtx[r] = 0.f;
      #pragma unroll
      for (int s=0;s<STATE_;s++) nBv[s] = 0.f;
    }
    float v = bias;
    #pragma unroll
    for (int r=0;r<DTR_;r++) v += dtx[r]*w[r];
    float dt = fsoftplus_(v);
    sdt += dt;
    float dx = dt * xcv;
    #pragma unroll
    for (int s=0;s<STATE_;s++) {
      float dA = fexp_(dt*A[s]);
      h[s] = dA*h[s] + dx*Bv[s];
    }
    #pragma unroll
    for (int r=0;r<DTR_;r++) dtx[r] = ndtx[r];
    #pragma unroll
    for (int s=0;s<STATE_;s++) Bv[s] = nBv[s];
    xcv = nxcv;
  }
  float* o = Pq + (size_t)idx*32;
  #pragma unroll
  for (int s=0;s<STATE_;s++) { o[s] = fexp_(A[s]*sdt); o[16+s] = h[s]; }
}

__global__ __launch_bounds__(256) void scan2_k(float* __restrict__ Pq)
{
  int idx = blockIdx.x*256 + threadIdx.x;   // 65536
  int s = idx & 15;
  int e = (idx >> 4) & (INNER_-1);
  int b = idx >> 15;
  float h = 0.f;
  for (int ch = 0; ch < NCH_; ch++) {
    size_t base = ((size_t)(b*NCH_+ch)*INNER_ + e)*32;
    float p = Pq[base + s];
    float q = Pq[base + 16 + s];
    Pq[base + 16 + s] = h;
    h = p*h + q;
  }
}

__global__ __launch_bounds__(256) void scan3_k(
    const float* __restrict__ xdbc, const float* __restrict__ xconv,
    const float* __restrict__ A_log, const float* __restrict__ dtw,
    const float* __restrict__ dtb, const float* __restrict__ Dp,
    const float* __restrict__ Pq, u16* __restrict__ ycat)
{
  int idx = blockIdx.x*256 + threadIdx.x;
  int e  = idx & (INNER_-1);
  int bc = idx >> 11;
  int ch = bc & (NCH_-1);
  int b  = bc >> 5;
  float A[STATE_];
  #pragma unroll
  for (int s=0;s<STATE_;s++) A[s] = -fexp_(A_log[e*STATE_+s]);
  float w[DTR_];
  #pragma unroll
  for (int r=0;r<DTR_;r++) w[r] = dtw[e*DTR_+r];
  float bias = dtb[e];
  float Dv = Dp[e];
  float h[STATE_];
  const float* hi = Pq + (size_t)idx*32 + 16;
  #pragma unroll
  for (int s=0;s<STATE_;s++) h[s] = hi[s];
  int mbase = b*L_ + ch*CHL_;
  float dtx[DTR_], Bv[STATE_], Cv[STATE_], xcv;
  {
    const float* row = xdbc + (size_t)mbase*40;
    #pragma unroll
    for (int r=0;r<DTR_;r++) dtx[r] = row[r];
    #pragma unroll
    for (int s=0;s<STATE_;s++) { Bv[s] = row[8+s]; Cv[s] = row[24+s]; }
    xcv = xconv[(size_t)mbase*INNER_ + e];
  }
  for (int l=0;l<CHL_;l++) {
    float ndtx[DTR_], nBv[STATE_], nCv[STATE_], nxcv = 0.f;
    if (l+1 < CHL_) {
      const float* nrow = xdbc + (size_t)(mbase+l+1)*40;
      #pragma unroll
      for (int r=0;r<DTR_;r++) ndtx[r] = nrow[r];
      #pragma unroll
      for (int s=0;s<STATE_;s++) { nBv[s] = nrow[8+s]; nCv[s] = nrow[24+s]; }
      nxcv = xconv[(size_t)(mbase+l+1)*INNER_ + e];
    } else {
      #pragma unroll
      for (int r=0;r<DTR_;r++) ndtx[r] = 0.f;
      #pragma unroll
      for (int s=0;s<STATE_;s++) { nBv[s] = 0.f; nCv[s] = 0.f; }
    }
    float v = bias;
    #pragma unroll
    for (int r=0;r<DTR_;r++) v += dtx[r]*w[r];
    float dt = fsoftplus_(v);
    float dx = dt * xcv;
    float y = 0.f;
    #pragma unroll
    for (int s=0;s<STATE_;s++) {
      float dA = fexp_(dt*A[s]);
      h[s] = dA*h[s] + dx*Bv[s];
      y += h[s]*Cv[s];
    }
    ycat[(size_t)(mbase+l)*4096 + e] = f2bf(y + xcv*Dv);
    #pragma unroll
    for (int r=0;r<DTR_;r++) dtx[r] = ndtx[r];
    #pragma unroll
    for (int s=0;s<STATE_;s++) { Bv[s] = nBv[s]; Cv[s] = nCv[s]; }
    xcv = nxcv;
  }
}

// ---------------- layernorm over summed out_proj partials + residual --------
__global__ __launch_bounds__(256) void ln2_k(const float* __restrict__ Q,
    const float* __restrict__ xres,
    const float* __restrict__ gma, const float* __restrict__ bta,
    float* __restrict__ out)
{
  int m = blockIdx.x;
  float s=0.f, s2=0.f;
  float v[4];
  #pragma unroll
  for (int j=0;j<4;j++) {
    int n = threadIdx.x + j*256;
    size_t idx = (size_t)m*DM_ + n;
    v[j] = Q[idx] + Q[2097152 + idx] + xres[idx];
    s += v[j]; s2 += v[j]*v[j];
  }
  #pragma unroll
  for (int off=32; off>=1; off>>=1) {
    s  += __shfl_down(s, off);
    s2 += __shfl_down(s2, off);
  }
  __shared__ float rs[4], rs2[4], stats[2];
  int wid = threadIdx.x >> 6;
  if ((threadIdx.x & 63) == 0) { rs[wid]=s; rs2[wid]=s2; }
  __syncthreads();
  if (threadIdx.x == 0) {
    float ts  = rs[0]+rs[1]+rs[2]+rs[3];
    float ts2 = rs2[0]+rs2[1]+rs2[2]+rs2[3];
    float mu  = ts/(float)DM_;
    float var = ts2/(float)DM_ - mu*mu;
    stats[0] = mu; stats[1] = rsqrtf(var + 1e-5f);
  }
  __syncthreads();
  float mu = stats[0], rstd = stats[1];
  #pragma unroll
  for (int j=0;j<4;j++) {
    int n = threadIdx.x + j*256;
    out[(size_t)m*DM_ + n] = (v[j]-mu)*rstd*gma[n] + bta[n];
  }
}

extern "C" void kernel_launch(void* const* d_in, const int* in_sizes, int n_in,
                              void* d_out, int out_size, void* d_ws, size_t ws_size,
                              hipStream_t stream)
{
  const float* x       = (const float*)d_in[0];
  const float* in_w    = (const float*)d_in[1];
  const float* conv_w  = (const float*)d_in[2];
  const float* conv_b  = (const float*)d_in[3];
  const float* A_log   = (const float*)d_in[4];
  const float* Dp      = (const float*)d_in[5];
  const float* xproj_w = (const float*)d_in[6];
  const float* dt_w    = (const float*)d_in[7];
  const float* dt_b    = (const float*)d_in[8];
  const float* f_re    = (const float*)d_in[9];
  const float* f_im    = (const float*)d_in[10];
  const float* s_dec   = (const float*)d_in[11];
  const float* fus_w   = (const float*)d_in[12];
  const float* fus_b   = (const float*)d_in[13];
  const float* out_w   = (const float*)d_in[14];
  const float* ln_g    = (const float*)d_in[15];
  const float* ln_b    = (const float*)d_in[16];
  float* out = (float*)d_out;

  // ---- workspace carve (fp32 region then bf16 region), ~137 MB total ----
  float* ws    = (float*)d_ws;
  float* xz    = ws;                       // 8388608  (M x 4096)
  float* xconv = xz    + 8388608;          // 4194304  (M x 2048)
  float* xdbc  = xconv + 4194304;          // 81920    (M x 40)
  float* Pq    = xdbc  + 81920;            // 4194304  (B*NCH*INNER x 32)
  u16* ub      = (u16*)(Pq + 4194304);
  u16* xb      = ub;                       // 2097152   x bf16; reused as Winv
  u16* inwb    = xb    + 2097152;          // 4194304   in_w bf16; reused as part
  u16* fuswb   = inwb  + 4194304;          // 8388608   fus_w bf16 (L1 aux)
  u16* outwb   = fuswb + 8388608;          // 2097152   out_w bf16 (L2 aux)
  u16* xt      = outwb + 2097152;          // 4194304   x_inner^T bf16; reused as ycomb
  u16* Wb      = xt    + 4194304;          // 1114112   Wdft (NFP_ x 1024)
  u16* XFb     = Wb    + 1114112;          // 4456448   (MD x NFP_) bf16
  u16* ycat    = XFb   + 4456448;          // 8388608   (M x 4096) bf16
  u16* ycomb   = xt;
  u16* Winv    = xb;                       // xb dead after L1
  float* part  = (float*)inwb;             // 1310720 f; inwb dead after L1
  u16* fpart   = (u16*)xconv;              // 8388608 u16 = xconv span (dead after scan3)
  float* opart = Pq;                       // 4194304 f (dead after scan3)

  // 0. convert x + in_w to bf16
  cvt2_k<<<CVT2_NT/1024, 256, 0, stream>>>(x, in_w, xb);

  // 1. xz = x @ in_proj_w^T (2048 x 4096 x 1024), plain f32 epilogue
  //    + aux genWdft (2176) + aux cvt fus_w (1024)
  mgemm_k<128,128,0,0,1,1><<<512 + 2176 + 1024, 512, 0, stream>>>(
      xb, inwb, xz, 1024, 4096, nullptr, nullptr, nullptr, nullptr, 32, 16,
      nullptr, nullptr, nullptr, Wb, 1024, fus_w, fuswb);
  // 2. conv+silu (writes xconv) + x_inner^T emit (writes xt, coalesced)
  //    + genWinv + cvt out_w   [standalone: 2048+4352+512 blocks]
  aux2_k<<<6912, 256, 0, stream>>>(xz, conv_w, conv_b, xconv, xt, Winv, out_w, outwb);
  // 3. forward DFT + spectral filter: XFb = filt(xt @ Wdft)  [544 GEMM blocks]
  //    + aux xproj (128, scalar-load version)
  mgemm_k<128,64,3,1,3,1><<<544 + SK_*8, 256, 0, stream>>>(
      xt, Wb, XFb, 1024, NFP_, f_re, nullptr, s_dec, f_im, 17, 32,
      xconv, xproj_w, part, nullptr, 1024, nullptr, nullptr);
  // 4. inverse DFT (4096 x 1024 x NFP_), LDS-transpose epilogue -> ycat[:,2048:]
  //    [512 GEMM blocks] + aux xpred (320)
  mgemm_k<128,64,6,1,4,1><<<512 + 320, 256, 0, stream>>>(
      XFb, Winv, ycat, NFP_, 0, nullptr, nullptr, nullptr, nullptr, 16, 32,
      part, nullptr, xdbc, nullptr, NFP_, nullptr, nullptr);
  // 5-7. chunked SSM scan -> y_cat[:, :2048] (bf16)
  scan1_k<<<(B_*NCH_*INNER_)/256, 256, 0, stream>>>(xdbc, xconv, A_log, dt_w, dt_b, Pq);
  scan2_k<<<(B_*INNER_*STATE_)/256, 256, 0, stream>>>(Pq);
  scan3_k<<<(B_*NCH_*INNER_)/256, 256, 0, stream>>>(xdbc, xconv, A_log, dt_w, dt_b, Dp, Pq, ycat);
  // 8a. fusion GEMM split-K x2 (2048 x 2048 x 4096), bf16 partials -> fpart
  mgemm_k<128,128,8,0,0,2><<<2*256, 512, 0, stream>>>(
      ycat, fuswb, fpart, 2048, 2048, nullptr, nullptr, nullptr, nullptr, 16, 16,
      nullptr, nullptr, nullptr, nullptr, 4096, nullptr, nullptr);
  // 8b. combine partials + gate epilogue -> ycomb bf16
  combine_gate_k<<<(2048*2048/4)/256, 256, 0, stream>>>(
      fpart, fus_b, ycat, xz, ycomb);
  // 9. out proj split-K x2 (2048 x 1024 x 2048) -> f32 partials in opart
  mgemm_k<64,64,7,1,0,2><<<2*512, 128, 0, stream>>>(
      ycomb, outwb, opart, 1024, 1024, nullptr, nullptr, nullptr, nullptr, 16, 32,
      nullptr, nullptr, nullptr, nullptr, 2048, nullptr, nullptr);
  // 10. layernorm over (partial0 + partial1 + residual) -> d_out
  ln2_k<<<M_, 256, 0, stream>>>(opart, x, ln_g, ln_b, out);
}

// Round 8
// 381.403 us; speedup vs baseline: 1.0463x; 1.0463x over previous
//
#include <hip/hip_runtime.h>
#include <math.h>

#define B_ 2
#define L_ 1024
#define DM_ 1024
#define STATE_ 16
#define CONV_ 4
#define DTR_ 8
#define INNER_ 2048
#define M_ (B_*L_)        /* 2048 rows (b,l) */
#define MD_ (B_*INNER_)   /* 4096 rows (b,c) */
#define NFFT_ 513
#define NFP_ 1088         /* 2*513=1026 padded to 17*64 */
#define NCH_ 32
#define CHL_ 32

typedef unsigned short u16;
typedef __attribute__((ext_vector_type(8))) short short8;
typedef __attribute__((ext_vector_type(8))) __bf16 bf16x8;
typedef __attribute__((ext_vector_type(4))) float f32x4;

__device__ __forceinline__ float frcp_(float x) { return __builtin_amdgcn_rcpf(x); }
__device__ __forceinline__ float fexp_(float x) { return __expf(x); }
__device__ __forceinline__ float fsigm_(float x) { return frcp_(1.f + __expf(-x)); }
__device__ __forceinline__ float fsilu_(float x) { return x * frcp_(1.f + __expf(-x)); }
__device__ __forceinline__ float fsoftplus_(float v) {
  return (v > 20.f) ? v : __logf(1.f + __expf(v));
}
__device__ __forceinline__ u16 f2bf(float f) {
  union { float f; unsigned u; } v; v.f = f;
  unsigned r = v.u + 0x7fffu + ((v.u >> 16) & 1u);
  return (u16)(r >> 16);
}
__device__ __forceinline__ float bf2f(u16 h) {
  union { unsigned u; float f; } v; v.u = ((unsigned)h) << 16;
  return v.f;
}
__device__ __forceinline__ void gload16(const void* g, void* l) {
  __builtin_amdgcn_global_load_lds(
      (const __attribute__((address_space(1))) unsigned*)g,
      (__attribute__((address_space(3))) unsigned*)l, 16, 0, 0);
}
__device__ __forceinline__ f32x4 mfma_bf16(short8 a, short8 b, f32x4 c) {
  return __builtin_amdgcn_mfma_f32_16x16x32_bf16(
      __builtin_bit_cast(bf16x8, a), __builtin_bit_cast(bf16x8, b), c, 0, 0, 0);
}

// ---------------- fp32 -> bf16 conversion (x + in_w only) -------------------
#define CVT2_N0 2097152
#define CVT2_NT 6291456
__global__ __launch_bounds__(256) void cvt2_k(
    const float* __restrict__ s0, const float* __restrict__ s1,
    u16* __restrict__ out)
{
  int i = (blockIdx.x*256 + threadIdx.x) * 4;
  const float* src; int off;
  if (i < CVT2_N0) { src = s0; off = 0; }
  else             { src = s1; off = CVT2_N0; }
  float4 v = *(const float4*)(src + (i - off));
  ushort4 o;
  o.x = f2bf(v.x); o.y = f2bf(v.y); o.z = f2bf(v.z); o.w = f2bf(v.w);
  *(ushort4*)(out + i) = o;
}

// ---------------- aux bodies ------------------------------------------------
// 16 contiguous floats per thread -> bf16
__device__ __forceinline__ void cvt16_body(int eb, int nthr, int t,
    const float* __restrict__ src, u16* __restrict__ dst)
{
  int i = (eb*nthr + t)*16;
  #pragma unroll
  for (int q = 0; q < 4; q++) {
    float4 v = *(const float4*)(src + i + q*4);
    ushort4 o;
    o.x = f2bf(v.x); o.y = f2bf(v.y); o.z = f2bf(v.z); o.w = f2bf(v.w);
    *(ushort4*)(dst + i + q*4) = o;
  }
}

// depthwise causal conv(4) + silu, 8 l per thread; ALSO emits x_inner^T bf16
// (pre-conv values) coalesced into xt[b*2048+c][l] for the DFT GEMM.
__device__ __forceinline__ void conv_xt_body(int idx, const float* __restrict__ xz,
    const float* __restrict__ cw, const float* __restrict__ cb,
    float* __restrict__ xc, u16* __restrict__ xt)
{
  int c = idx & (INNER_-1);
  int g = idx >> 11;                        // 0..255
  int b = g >> 7;
  int lb = (g & 127) * 8;
  float w0=cw[c*4+0], w1=cw[c*4+1], w2=cw[c*4+2], w3=cw[c*4+3];
  float bias = cb[c];
  float v[11];
  #pragma unroll
  for (int j = 0; j < 11; j++) {
    int l = lb - 3 + j;
    v[j] = (l >= 0) ? xz[((size_t)((b << 10) + l))*4096 + c] : 0.f;
  }
  union { u16 a[8]; short8 v8; } tu;
  #pragma unroll
  for (int j = 0; j < 8; j++) tu.a[j] = f2bf(v[j+3]);
  *(short8*)&xt[(((size_t)(b*INNER_ + c)) << 10) + lb] = tu.v8;
  #pragma unroll
  for (int j = 0; j < 8; j++) {
    float s = bias + w0*v[j] + w1*v[j+1] + w2*v[j+2] + w3*v[j+3];
    xc[((size_t)((b << 10) + lb + j))*INNER_ + c] = fsilu_(s);
  }
}

// DFT matrix (bf16, K-contiguous): W[col*1024 + l], col < NFP_
__device__ __forceinline__ void genWdft_body(int idx, u16* __restrict__ W)
{
  int l = idx & (L_-1);
  int col = idx >> 10;
  float v = 0.f;
  int f = col >> 1;
  if (f < NFFT_) {
    int ph = (l*f) & (L_-1);
    float th = (float)ph * (6.283185307179586f / (float)L_);
    v = (col & 1) ? -__sinf(th) : __cosf(th);
  }
  W[idx] = f2bf(v);
}

// inverse-DFT matrix: W[l*NFP_ + r], l < 1024, r < NFP_
__device__ __forceinline__ void genWinv_body(int idx, u16* __restrict__ W)
{
  int r = idx % NFP_;
  int l = idx / NFP_;
  int f = r >> 1;
  float v = 0.f;
  if (f < NFFT_) {
    bool edge = (f == 0) || (f == 512);
    float sc = (edge ? 1.f : 2.f) / (float)L_;
    int ph = (f*l) & (L_-1);
    float th = (float)ph * (6.283185307179586f / (float)L_);
    if (r & 1) v = edge ? 0.f : -sc*__sinf(th);
    else       v = sc*__cosf(th);
  }
  W[idx] = f2bf(v);
}

// ---------------- standalone aux launch: conv+xt, genWinv, cvts -------------
__global__ __launch_bounds__(256) void aux2_k(
    const float* __restrict__ xz, const float* __restrict__ cw,
    const float* __restrict__ cb, float* __restrict__ xc,
    u16* __restrict__ xt, u16* __restrict__ Winv,
    const float* __restrict__ ows, u16* __restrict__ owd,
    const float* __restrict__ xpws, u16* __restrict__ xpwd)
{
  int eb = blockIdx.x;
  if (eb < 2048)      conv_xt_body(eb*256 + threadIdx.x, xz, cw, cb, xc, xt);
  else if (eb < 6400) genWinv_body((eb - 2048)*256 + threadIdx.x, Winv);
  else if (eb < 6912) cvt16_body(eb - 6400, 256, threadIdx.x, ows, owd);
  else                cvt16_body(eb - 6912, 256, threadIdx.x, xpws, xpwd);
}

// ---------------- bf16 MFMA GEMM (templated tile, double-buffered) ----------
// C[m,n] = sum_k A[m,k0+k]*Bt[n,k0+k], k < K (per-split), row stride ldk.
// KS splits along K; split ks = bid/(gx*gy), k0 = ks*K.
// AUX blocks beyond KS*gx*gy: 1 = genWdft + cvt16 fus_w; 3 = cvt16 xconv->xcb.
// All independent of this launch's GEMM + disjoint memory (audited).
// EPI: 0 plain f32; 3 spectral filter (bf16); 6 inv-DFT via LDS-transpose
//      (coalesced 16B stores into ycat[:,2048:]); 7 f32 split-K partial;
//      8 bf16 split-K partial; 9 x_dbc (f32, n<40 only, ldc=40).
template<int TM, int TN, int EPI, int YCH, int AUX, int KS>
__global__ __launch_bounds__((TM/64)*(TN/32)*64) void mgemm_k(
    const u16* __restrict__ Ab, const u16* __restrict__ Bb,
    void* __restrict__ Cout, int K, int ldc,
    const float* __restrict__ aux0, u16* __restrict__ aux1,
    const float* __restrict__ aux2, const float* __restrict__ aux3,
    int gx, int gy,
    u16* __restrict__ gw,
    int ldk, const float* __restrict__ cvs, u16* __restrict__ cvd)
{
  constexpr int WN   = TN/32;
  constexpr int NW   = (TM/64)*WN;
  constexpr int NTHR = NW*64;
  __shared__ __align__(16) u16 As[2][TM*64];
  __shared__ __align__(16) u16 Bs[2][TN*64];
  const int t = threadIdx.x;
  const int nwg = gx * gy;

  if constexpr (AUX != 0) {
    int eb = (int)blockIdx.x - nwg*KS;
    if (eb >= 0) {
      if constexpr (AUX == 1) {              // genWdft (2176) + cvt fus_w (1024)
        if (eb < 2176) genWdft_body(eb*NTHR + t, gw);
        else           cvt16_body(eb - 2176, NTHR, t, cvs, cvd);
      } else {                               // 3: cvt16 xconv -> xcb (1024)
        cvt16_body(eb, NTHR, t, cvs, cvd);
      }
      return;
    }
  }

  const int lane = t & 63;
  const int w = t >> 6;
  const int wm = w / WN, wn = w % WN;

  // split-K id + XCD-chunked bijective remap (nwg % 8 == 0 everywhere)
  int bid = blockIdx.x;
  int ks = 0;
  if constexpr (KS > 1) { ks = bid / nwg; bid -= ks*nwg; }
  const int k0 = ks * K;
  const int lid = (bid & 7) * (nwg >> 3) + (bid >> 3);
  int bx, by;
  if (YCH) { by = lid / gx; bx = lid - by*gx; }
  else     { bx = lid / gy; by = lid - bx*gy; }
  const int M0 = by * TM, N0 = bx * TN;

  f32x4 acc[4][2] = {};

  auto stage = [&](int buf, int kk0) {
    #pragma unroll
    for (int q = 0; q < TM*8/NTHR; q++) {
      int u = q*NTHR + t;
      int row = u >> 3, gpr = u & 7;
      int grp = gpr ^ (row & 7);        // XOR swizzle
      gload16(Ab + (size_t)(M0+row)*ldk + k0 + kk0 + grp*8, &As[buf][u*8]);
    }
    #pragma unroll
    for (int q = 0; q < TN*8/NTHR; q++) {
      int u = q*NTHR + t;
      int row = u >> 3, gpr = u & 7;
      int grp = gpr ^ (row & 7);
      gload16(Bb + (size_t)(N0+row)*ldk + k0 + kk0 + grp*8, &Bs[buf][u*8]);
    }
  };

  stage(0, 0);
  const int nk = K >> 6;
  for (int kst = 0; kst < nk; kst++) {
    const int buf = kst & 1;
    __syncthreads();                    // drain stage(buf); protect buf^1 overwrite
    if (kst + 1 < nk) stage(buf ^ 1, (kst + 1) << 6);
    const u16* Asb = As[buf];
    const u16* Bsb = Bs[buf];
    #pragma unroll
    for (int kk = 0; kk < 2; kk++) {
      const int quad = lane >> 4;
      const int grp = kk*4 + quad;
      short8 af[4], bfr[2];
      #pragma unroll
      for (int i = 0; i < 4; i++) {
        int row = wm*64 + i*16 + (lane & 15);
        af[i] = *(const short8*)&Asb[(row*8 + (grp ^ (row & 7)))*8];
      }
      #pragma unroll
      for (int j = 0; j < 2; j++) {
        int row = wn*32 + j*16 + (lane & 15);
        bfr[j] = *(const short8*)&Bsb[(row*8 + (grp ^ (row & 7)))*8];
      }
      #pragma unroll
      for (int i = 0; i < 4; i++)
        #pragma unroll
        for (int j = 0; j < 2; j++)
          acc[i][j] = mfma_bf16(af[i], bfr[j], acc[i][j]);
    }
  }

  if constexpr (EPI == 6) {
    // LDS-transpose epilogue: tile [c_loc 128][l_loc 64] -> coalesced 16B
    // stores into ycat[(b,l) row][2048 + c]. Pad 66 breaks bank aliasing.
    u16* T = (u16*)&As[0][0];           // 128*66*2 = 16.9KB <= 32KB As
    __syncthreads();                    // all waves done reading As
    #pragma unroll
    for (int i = 0; i < 4; i++) {
      int cb = wm*64 + i*16 + (lane >> 4)*4;
      #pragma unroll
      for (int j = 0; j < 2; j++) {
        int ll = wn*32 + j*16 + (lane & 15);
        #pragma unroll
        for (int r = 0; r < 4; r++)
          T[(cb + r)*66 + ll] = f2bf(acc[i][j][r]);
      }
    }
    __syncthreads();
    const int b2 = M0 >> 11, c0 = M0 & (INNER_-1);
    u16* yc = (u16*)Cout;
    #pragma unroll
    for (int q = 0; q < (TM*TN/8)/NTHR; q++) {
      int task = q*NTHR + t;
      int cg = task & 15, ll = task >> 4;
      union { u16 a[8]; short8 v8; } tu;
      #pragma unroll
      for (int e = 0; e < 8; e++) tu.a[e] = T[(cg*8 + e)*66 + ll];
      *(short8*)&yc[((size_t)((b2 << 10) + N0 + ll) << 12) + 2048 + c0 + cg*8] = tu.v8;
    }
  } else {
    // C/D layout: col = lane&15, row = (lane>>4)*4 + r
    #pragma unroll
    for (int i = 0; i < 4; i++) {
      int mbase = M0 + wm*64 + i*16 + (lane >> 4)*4;
      #pragma unroll
      for (int j = 0; j < 2; j++) {
        int n = N0 + wn*32 + j*16 + (lane & 15);
        #pragma unroll
        for (int r = 0; r < 4; r++) {
          int m = mbase + r;
          float v = acc[i][j][r];
          if (EPI == 0) {
            ((float*)Cout)[(size_t)m*ldc + n] = v;
          } else if (EPI == 3) {        // spectral filter, complex pair via shfl
            float pv = __shfl_xor(v, 1, 64);
            int f = n >> 1;
            float outv = 0.f;
            if (f < NFFT_) {
              int c = m & (INNER_-1);
              float d  = fexp_(-aux2[c] * (float)f * (1.f/512.f));
              float wr = aux0[c*NFFT_+f]*d, wi = aux3[c*NFFT_+f]*d;
              float a = (n & 1) ? pv : v;
              float b = (n & 1) ? v : pv;
              outv = (n & 1) ? (a*wi + b*wr) : (a*wr - b*wi);
            }
            ((u16*)Cout)[(size_t)m*ldc + n] = f2bf(outv);
          } else if (EPI == 7) {        // f32 split-K partial
            float* P = (float*)Cout + (size_t)ks * ((size_t)gy*TM*ldc);
            P[(size_t)m*ldc + n] = v;
          } else if (EPI == 8) {        // bf16 split-K partial
            u16* P = (u16*)Cout + (size_t)ks * ((size_t)gy*TM*ldc);
            P[(size_t)m*ldc + n] = f2bf(v);
          } else {                      // 9: x_dbc, n<40 only
            if (n < 40) ((float*)Cout)[(size_t)m*40 + n] = v;
          }
        }
      }
    }
  }
}

// ---------------- fusion combine: gate epilogue over bf16 partials ----------
__global__ __launch_bounds__(256) void combine_gate_k(
    const u16* __restrict__ P, const float* __restrict__ fus_b,
    const u16* __restrict__ ycat, const float* __restrict__ xz,
    u16* __restrict__ ycomb)
{
  int i4 = (blockIdx.x*256 + threadIdx.x)*4;   // m*2048 + n
  int m = i4 >> 11, n = i4 & 2047;
  ushort4 p0 = *(const ushort4*)(P + i4);
  ushort4 p1 = *(const ushort4*)(P + 4194304 + i4);
  ushort4 ysv = *(const ushort4*)(ycat + (size_t)m*4096 + n);
  ushort4 ypv = *(const ushort4*)(ycat + (size_t)m*4096 + 2048 + n);
  float4 zv = *(const float4*)(xz + (size_t)m*4096 + 2048 + n);
  float4 fb = *(const float4*)(fus_b + n);
  float pp[4] = {bf2f(p0.x)+bf2f(p1.x), bf2f(p0.y)+bf2f(p1.y),
                 bf2f(p0.z)+bf2f(p1.z), bf2f(p0.w)+bf2f(p1.w)};
  float zz[4] = {zv.x, zv.y, zv.z, zv.w};
  float bb[4] = {fb.x, fb.y, fb.z, fb.w};
  u16 ys[4] = {ysv.x, ysv.y, ysv.z, ysv.w};
  u16 yp[4] = {ypv.x, ypv.y, ypv.z, ypv.w};
  ushort4 o;
  u16* op = (u16*)&o;
  #pragma unroll
  for (int j = 0; j < 4; j++) {
    float g = fsigm_(pp[j] + bb[j]);
    op[j] = f2bf((g*bf2f(ys[j]) + (1.f-g)*bf2f(yp[j]))*fsilu_(zz[j]));
  }
  *(ushort4*)(ycomb + i4) = o;
}

// ---------------- SSM chunked scan (prefetched) ----------------
__global__ __launch_bounds__(256) void scan1_k(
    const float* __restrict__ xdbc, const float* __restrict__ xconv,
    const float* __restrict__ A_log, const float* __restrict__ dtw,
    const float* __restrict__ dtb, float* __restrict__ Pq)
{
  int idx = blockIdx.x*256 + threadIdx.x;   // (b*NCH+ch)*INNER + e
  int e  = idx & (INNER_-1);
  int bc = idx >> 11;
  int ch = bc & (NCH_-1);
  int b  = bc >> 5;
  float A[STATE_];
  #pragma unroll
  for (int s=0;s<STATE_;s++) A[s] = -fexp_(A_log[e*STATE_+s]);
  float w[DTR_];
  #pragma unroll
  for (int r=0;r<DTR_;r++) w[r] = dtw[e*DTR_+r];
  float bias = dtb[e];
  float h[STATE_] = {};
  float sdt = 0.f;
  int mbase = b*L_ + ch*CHL_;
  float dtx[DTR_], Bv[STATE_], xcv;
  {
    const float* row = xdbc + (size_t)mbase*40;
    #pragma unroll
    for (int r=0;r<DTR_;r++) dtx[r] = row[r];
    #pragma unroll
    for (int s=0;s<STATE_;s++) Bv[s] = row[8+s];
    xcv = xconv[(size_t)mbase*INNER_ + e];
  }
  for (int l=0;l<CHL_;l++) {
    float ndtx[DTR_], nBv[STATE_], nxcv = 0.f;
    if (l+1 < CHL_) {
      const float* nrow = xdbc + (size_t)(mbase+l+1)*40;
      #pragma unroll
      for (int r=0;r<DTR_;r++) ndtx[r] = nrow[r];
      #pragma unroll
      for (int s=0;s<STATE_;s++) nBv[s] = nrow[8+s];
      nxcv = xconv[(size_t)(mbase+l+1)*INNER_ + e];
    } else {
      #pragma unroll
      for (int r=0;r<DTR_;r++) ndtx[r] = 0.f;
      #pragma unroll
      for (int s=0;s<STATE_;s++) nBv[s] = 0.f;
    }
    float v = bias;
    #pragma unroll
    for (int r=0;r<DTR_;r++) v += dtx[r]*w[r];
    float dt = fsoftplus_(v);
    sdt += dt;
    float dx = dt * xcv;
    #pragma unroll
    for (int s=0;s<STATE_;s++) {
      float dA = fexp_(dt*A[s]);
      h[s] = dA*h[s] + dx*Bv[s];
    }
    #pragma unroll
    for (int r=0;r<DTR_;r++) dtx[r] = ndtx[r];
    #pragma unroll
    for (int s=0;s<STATE_;s++) Bv[s] = nBv[s];
    xcv = nxcv;
  }
  float* o = Pq + (size_t)idx*32;
  #pragma unroll
  for (int s=0;s<STATE_;s++) { o[s] = fexp_(A[s]*sdt); o[16+s] = h[s]; }
}

__global__ __launch_bounds__(256) void scan2_k(float* __restrict__ Pq)
{
  int idx = blockIdx.x*256 + threadIdx.x;   // 65536
  int s = idx & 15;
  int e = (idx >> 4) & (INNER_-1);
  int b = idx >> 15;
  float h = 0.f;
  for (int ch = 0; ch < NCH_; ch++) {
    size_t base = ((size_t)(b*NCH_+ch)*INNER_ + e)*32;
    float p = Pq[base + s];
    float q = Pq[base + 16 + s];
    Pq[base + 16 + s] = h;
    h = p*h + q;
  }
}

__global__ __launch_bounds__(256) void scan3_k(
    const float* __restrict__ xdbc, const float* __restrict__ xconv,
    const float* __restrict__ A_log, const float* __restrict__ dtw,
    const float* __restrict__ dtb, const float* __restrict__ Dp,
    const float* __restrict__ Pq, u16* __restrict__ ycat)
{
  int idx = blockIdx.x*256 + threadIdx.x;
  int e  = idx & (INNER_-1);
  int bc = idx >> 11;
  int ch = bc & (NCH_-1);
  int b  = bc >> 5;
  float A[STATE_];
  #pragma unroll
  for (int s=0;s<STATE_;s++) A[s] = -fexp_(A_log[e*STATE_+s]);
  float w[DTR_];
  #pragma unroll
  for (int r=0;r<DTR_;r++) w[r] = dtw[e*DTR_+r];
  float bias = dtb[e];
  float Dv = Dp[e];
  float h[STATE_];
  const float* hi = Pq + (size_t)idx*32 + 16;
  #pragma unroll
  for (int s=0;s<STATE_;s++) h[s] = hi[s];
  int mbase = b*L_ + ch*CHL_;
  float dtx[DTR_], Bv[STATE_], Cv[STATE_], xcv;
  {
    const float* row = xdbc + (size_t)mbase*40;
    #pragma unroll
    for (int r=0;r<DTR_;r++) dtx[r] = row[r];
    #pragma unroll
    for (int s=0;s<STATE_;s++) { Bv[s] = row[8+s]; Cv[s] = row[24+s]; }
    xcv = xconv[(size_t)mbase*INNER_ + e];
  }
  for (int l=0;l<CHL_;l++) {
    float ndtx[DTR_], nBv[STATE_], nCv[STATE_], nxcv = 0.f;
    if (l+1 < CHL_) {
      const float* nrow = xdbc + (size_t)(mbase+l+1)*40;
      #pragma unroll
      for (int r=0;r<DTR_;r++) ndtx[r] = nrow[r];
      #pragma unroll
      for (int s=0;s<STATE_;s++) { nBv[s] = nrow[8+s]; nCv[s] = nrow[24+s]; }
      nxcv = xconv[(size_t)(mbase+l+1)*INNER_ + e];
    } else {
      #pragma unroll
      for (int r=0;r<DTR_;r++) ndtx[r] = 0.f;
      #pragma unroll
      for (int s=0;s<STATE_;s++) { nBv[s] = 0.f; nCv[s] = 0.f; }
    }
    float v = bias;
    #pragma unroll
    for (int r=0;r<DTR_;r++) v += dtx[r]*w[r];
    float dt = fsoftplus_(v);
    float dx = dt * xcv;
    float y = 0.f;
    #pragma unroll
    for (int s=0;s<STATE_;s++) {
      float dA = fexp_(dt*A[s]);
      h[s] = dA*h[s] + dx*Bv[s];
      y += h[s]*Cv[s];
    }
    ycat[(size_t)(mbase+l)*4096 + e] = f2bf(y + xcv*Dv);
    #pragma unroll
    for (int r=0;r<DTR_;r++) dtx[r] = ndtx[r];
    #pragma unroll
    for (int s=0;s<STATE_;s++) { Bv[s] = nBv[s]; Cv[s] = nCv[s]; }
    xcv = nxcv;
  }
}

// ---------------- layernorm over summed out_proj partials + residual --------
__global__ __launch_bounds__(256) void ln2_k(const float* __restrict__ Q,
    const float* __restrict__ xres,
    const float* __restrict__ gma, const float* __restrict__ bta,
    float* __restrict__ out)
{
  int m = blockIdx.x;
  float s=0.f, s2=0.f;
  float v[4];
  #pragma unroll
  for (int j=0;j<4;j++) {
    int n = threadIdx.x + j*256;
    size_t idx = (size_t)m*DM_ + n;
    v[j] = Q[idx] + Q[2097152 + idx] + xres[idx];
    s += v[j]; s2 += v[j]*v[j];
  }
  #pragma unroll
  for (int off=32; off>=1; off>>=1) {
    s  += __shfl_down(s, off);
    s2 += __shfl_down(s2, off);
  }
  __shared__ float rs[4], rs2[4], stats[2];
  int wid = threadIdx.x >> 6;
  if ((threadIdx.x & 63) == 0) { rs[wid]=s; rs2[wid]=s2; }
  __syncthreads();
  if (threadIdx.x == 0) {
    float ts  = rs[0]+rs[1]+rs[2]+rs[3];
    float ts2 = rs2[0]+rs2[1]+rs2[2]+rs2[3];
    float mu  = ts/(float)DM_;
    float var = ts2/(float)DM_ - mu*mu;
    stats[0] = mu; stats[1] = rsqrtf(var + 1e-5f);
  }
  __syncthreads();
  float mu = stats[0], rstd = stats[1];
  #pragma unroll
  for (int j=0;j<4;j++) {
    int n = threadIdx.x + j*256;
    out[(size_t)m*DM_ + n] = (v[j]-mu)*rstd*gma[n] + bta[n];
  }
}

extern "C" void kernel_launch(void* const* d_in, const int* in_sizes, int n_in,
                              void* d_out, int out_size, void* d_ws, size_t ws_size,
                              hipStream_t stream)
{
  const float* x       = (const float*)d_in[0];
  const float* in_w    = (const float*)d_in[1];
  const float* conv_w  = (const float*)d_in[2];
  const float* conv_b  = (const float*)d_in[3];
  const float* A_log   = (const float*)d_in[4];
  const float* Dp      = (const float*)d_in[5];
  const float* xproj_w = (const float*)d_in[6];
  const float* dt_w    = (const float*)d_in[7];
  const float* dt_b    = (const float*)d_in[8];
  const float* f_re    = (const float*)d_in[9];
  const float* f_im    = (const float*)d_in[10];
  const float* s_dec   = (const float*)d_in[11];
  const float* fus_w   = (const float*)d_in[12];
  const float* fus_b   = (const float*)d_in[13];
  const float* out_w   = (const float*)d_in[14];
  const float* ln_g    = (const float*)d_in[15];
  const float* ln_b    = (const float*)d_in[16];
  float* out = (float*)d_out;

  // ---- workspace carve (fp32 region then bf16 region), ~137 MB total ----
  float* ws    = (float*)d_ws;
  float* xz    = ws;                       // 8388608  (M x 4096)
  float* xconv = xz    + 8388608;          // 4194304  (M x 2048)
  float* xdbc  = xconv + 4194304;          // 81920    (M x 40)
  float* Pq    = xdbc  + 81920;            // 4194304  (B*NCH*INNER x 32)
  u16* ub      = (u16*)(Pq + 4194304);
  u16* xb      = ub;                       // 2097152   x bf16; reused: Winv + xpwb
  u16* inwb    = xb    + 2097152;          // 4194304   in_w bf16; reused as xcb
  u16* fuswb   = inwb  + 4194304;          // 8388608   fus_w bf16 (L1 aux)
  u16* outwb   = fuswb + 8388608;          // 2097152   out_w bf16 (L2 aux)
  u16* xt      = outwb + 2097152;          // 4194304   x_inner^T bf16; reused as ycomb
  u16* Wb      = xt    + 4194304;          // 1114112   Wdft (NFP_ x 1024)
  u16* XFb     = Wb    + 1114112;          // 4456448   (MD x NFP_) bf16
  u16* ycat    = XFb   + 4456448;          // 8388608   (M x 4096) bf16
  u16* ycomb   = xt;
  u16* Winv    = xb;                       // 1114112; xb dead after L1
  u16* xpwb    = xb + 1114112;             // 81920 (xproj_w bf16); pad rows 40-63
                                           // read leftover finite x-bf16 (no NaN)
  u16* xcb     = inwb;                     // 4194304 u16 (xconv bf16); inwb dead after L1
  u16* fpart   = (u16*)xconv;              // 8388608 u16 (dead after scan3)
  float* opart = Pq;                       // 4194304 f (dead after scan3)

  // 0. convert x + in_w to bf16
  cvt2_k<<<CVT2_NT/1024, 256, 0, stream>>>(x, in_w, xb);

  // 1. xz = x @ in_proj_w^T (2048 x 4096 x 1024), plain f32 epilogue
  //    + aux genWdft (2176) + aux cvt fus_w (1024)
  mgemm_k<128,128,0,0,1,1><<<512 + 2176 + 1024, 512, 0, stream>>>(
      xb, inwb, xz, 1024, 4096, nullptr, nullptr, nullptr, nullptr, 32, 16,
      Wb, 1024, fus_w, fuswb);
  // 2. conv+silu (xconv) + x_inner^T emit (xt) + genWinv + cvt out_w + cvt xproj_w
  aux2_k<<<6932, 256, 0, stream>>>(xz, conv_w, conv_b, xconv, xt, Winv,
                                   out_w, outwb, xproj_w, xpwb);
  // 3. forward DFT + spectral filter: XFb = filt(xt @ Wdft)  [544 GEMM blocks]
  //    + aux cvt xconv -> xcb bf16 (1024 blocks)
  mgemm_k<128,64,3,1,3,1><<<544 + 1024, 256, 0, stream>>>(
      xt, Wb, XFb, 1024, NFP_, f_re, nullptr, s_dec, f_im, 17, 32,
      nullptr, 1024, xconv, xcb);
  // 3.5 x_dbc = xconv @ x_proj_w^T as bf16 MFMA GEMM (2048 x 40(->64) x 2048)
  mgemm_k<128,64,9,1,0,1><<<16, 256, 0, stream>>>(
      xcb, xpwb, xdbc, 2048, 40, nullptr, nullptr, nullptr, nullptr, 1, 16,
      nullptr, 2048, nullptr, nullptr);
  // 4. inverse DFT (4096 x 1024 x NFP_), LDS-transpose epilogue -> ycat[:,2048:]
  mgemm_k<128,64,6,1,0,1><<<512, 256, 0, stream>>>(
      XFb, Winv, ycat, NFP_, 0, nullptr, nullptr, nullptr, nullptr, 16, 32,
      nullptr, NFP_, nullptr, nullptr);
  // 5-7. chunked SSM scan -> y_cat[:, :2048] (bf16)
  scan1_k<<<(B_*NCH_*INNER_)/256, 256, 0, stream>>>(xdbc, xconv, A_log, dt_w, dt_b, Pq);
  scan2_k<<<(B_*INNER_*STATE_)/256, 256, 0, stream>>>(Pq);
  scan3_k<<<(B_*NCH_*INNER_)/256, 256, 0, stream>>>(xdbc, xconv, A_log, dt_w, dt_b, Dp, Pq, ycat);
  // 8a. fusion GEMM split-K x2 (2048 x 2048 x 4096), bf16 partials -> fpart
  mgemm_k<128,128,8,0,0,2><<<2*256, 512, 0, stream>>>(
      ycat, fuswb, fpart, 2048, 2048, nullptr, nullptr, nullptr, nullptr, 16, 16,
      nullptr, 4096, nullptr, nullptr);
  // 8b. combine partials + gate epilogue -> ycomb bf16
  combine_gate_k<<<(2048*2048/4)/256, 256, 0, stream>>>(
      fpart, fus_b, ycat, xz, ycomb);
  // 9. out proj split-K x2 (2048 x 1024 x 2048) -> f32 partials in opart
  mgemm_k<64,64,7,1,0,2><<<2*512, 128, 0, stream>>>(
      ycomb, outwb, opart, 1024, 1024, nullptr, nullptr, nullptr, nullptr, 16, 32,
      nullptr, 2048, nullptr, nullptr);
  // 10. layernorm over (partial0 + partial1 + residual) -> d_out
  ln2_k<<<M_, 256, 0, stream>>>(opart, x, ln_g, ln_b, out);
}

// Round 10
// 368.576 us; speedup vs baseline: 1.0827x; 1.0348x over previous
//
#include <hip/hip_runtime.h>
#include <math.h>

#define B_ 2
#define L_ 1024
#define DM_ 1024
#define STATE_ 16
#define CONV_ 4
#define DTR_ 8
#define INNER_ 2048
#define M_ (B_*L_)        /* 2048 rows (b,l) */
#define MD_ (B_*INNER_)   /* 4096 rows (b,c) */
#define NFFT_ 513
#define NFP_ 1088         /* 2*513=1026 padded to 17*64 */
#define NCH_ 32
#define CHL_ 32

typedef unsigned short u16;
typedef __attribute__((ext_vector_type(8))) short short8;
typedef __attribute__((ext_vector_type(8))) __bf16 bf16x8;
typedef __attribute__((ext_vector_type(4))) float f32x4;

__device__ __forceinline__ float frcp_(float x) { return __builtin_amdgcn_rcpf(x); }
__device__ __forceinline__ float fexp_(float x) { return __expf(x); }
__device__ __forceinline__ float fsigm_(float x) { return frcp_(1.f + __expf(-x)); }
__device__ __forceinline__ float fsilu_(float x) { return x * frcp_(1.f + __expf(-x)); }
__device__ __forceinline__ float fsoftplus_(float v) {
  return (v > 20.f) ? v : __logf(1.f + __expf(v));
}
__device__ __forceinline__ u16 f2bf(float f) {
  union { float f; unsigned u; } v; v.f = f;
  unsigned r = v.u + 0x7fffu + ((v.u >> 16) & 1u);
  return (u16)(r >> 16);
}
__device__ __forceinline__ float bf2f(u16 h) {
  union { unsigned u; float f; } v; v.u = ((unsigned)h) << 16;
  return v.f;
}
__device__ __forceinline__ void gload16(const void* g, void* l) {
  __builtin_amdgcn_global_load_lds(
      (const __attribute__((address_space(1))) unsigned*)g,
      (__attribute__((address_space(3))) unsigned*)l, 16, 0, 0);
}
__device__ __forceinline__ f32x4 mfma_bf16(short8 a, short8 b, f32x4 c) {
  return __builtin_amdgcn_mfma_f32_16x16x32_bf16(
      __builtin_bit_cast(bf16x8, a), __builtin_bit_cast(bf16x8, b), c, 0, 0, 0);
}

// ---------------- fp32 -> bf16 conversion (x + in_w only) -------------------
#define CVT2_N0 2097152
#define CVT2_NT 6291456
__global__ __launch_bounds__(256) void cvt2_k(
    const float* __restrict__ s0, const float* __restrict__ s1,
    u16* __restrict__ out)
{
  int i = (blockIdx.x*256 + threadIdx.x) * 4;
  const float* src; int off;
  if (i < CVT2_N0) { src = s0; off = 0; }
  else             { src = s1; off = CVT2_N0; }
  float4 v = *(const float4*)(src + (i - off));
  ushort4 o;
  o.x = f2bf(v.x); o.y = f2bf(v.y); o.z = f2bf(v.z); o.w = f2bf(v.w);
  *(ushort4*)(out + i) = o;
}

// ---------------- aux bodies ------------------------------------------------
// 16 contiguous floats per thread -> bf16
__device__ __forceinline__ void cvt16_body(int eb, int nthr, int t,
    const float* __restrict__ src, u16* __restrict__ dst)
{
  int i = (eb*nthr + t)*16;
  #pragma unroll
  for (int q = 0; q < 4; q++) {
    float4 v = *(const float4*)(src + i + q*4);
    ushort4 o;
    o.x = f2bf(v.x); o.y = f2bf(v.y); o.z = f2bf(v.z); o.w = f2bf(v.w);
    *(ushort4*)(dst + i + q*4) = o;
  }
}

// depthwise causal conv(4) + silu, 8 l per thread; ALSO emits x_inner^T bf16
// (pre-conv values) coalesced into xt[b*2048+c][l] for the DFT GEMM.
__device__ __forceinline__ void conv_xt_body(int idx, const float* __restrict__ xz,
    const float* __restrict__ cw, const float* __restrict__ cb,
    float* __restrict__ xc, u16* __restrict__ xt)
{
  int c = idx & (INNER_-1);
  int g = idx >> 11;                        // 0..255
  int b = g >> 7;
  int lb = (g & 127) * 8;
  float w0=cw[c*4+0], w1=cw[c*4+1], w2=cw[c*4+2], w3=cw[c*4+3];
  float bias = cb[c];
  float v[11];
  #pragma unroll
  for (int j = 0; j < 11; j++) {
    int l = lb - 3 + j;
    v[j] = (l >= 0) ? xz[((size_t)((b << 10) + l))*4096 + c] : 0.f;
  }
  union { u16 a[8]; short8 v8; } tu;
  #pragma unroll
  for (int j = 0; j < 8; j++) tu.a[j] = f2bf(v[j+3]);
  *(short8*)&xt[(((size_t)(b*INNER_ + c)) << 10) + lb] = tu.v8;
  #pragma unroll
  for (int j = 0; j < 8; j++) {
    float s = bias + w0*v[j] + w1*v[j+1] + w2*v[j+2] + w3*v[j+3];
    xc[((size_t)((b << 10) + lb + j))*INNER_ + c] = fsilu_(s);
  }
}

// DFT matrix (bf16, K-contiguous): W[col*1024 + l], col < NFP_
__device__ __forceinline__ void genWdft_body(int idx, u16* __restrict__ W)
{
  int l = idx & (L_-1);
  int col = idx >> 10;
  float v = 0.f;
  int f = col >> 1;
  if (f < NFFT_) {
    int ph = (l*f) & (L_-1);
    float th = (float)ph * (6.283185307179586f / (float)L_);
    v = (col & 1) ? -__sinf(th) : __cosf(th);
  }
  W[idx] = f2bf(v);
}

// inverse-DFT matrix: W[l*NFP_ + r], l < 1024, r < NFP_
__device__ __forceinline__ void genWinv_body(int idx, u16* __restrict__ W)
{
  int r = idx % NFP_;
  int l = idx / NFP_;
  int f = r >> 1;
  float v = 0.f;
  if (f < NFFT_) {
    bool edge = (f == 0) || (f == 512);
    float sc = (edge ? 1.f : 2.f) / (float)L_;
    int ph = (f*l) & (L_-1);
    float th = (float)ph * (6.283185307179586f / (float)L_);
    if (r & 1) v = edge ? 0.f : -sc*__sinf(th);
    else       v = sc*__cosf(th);
  }
  W[idx] = f2bf(v);
}

// ---------------- standalone aux launch: conv+xt, genWinv, cvts -------------
__global__ __launch_bounds__(256) void aux2_k(
    const float* __restrict__ xz, const float* __restrict__ cw,
    const float* __restrict__ cb, float* __restrict__ xc,
    u16* __restrict__ xt, u16* __restrict__ Winv,
    const float* __restrict__ ows, u16* __restrict__ owd,
    const float* __restrict__ xpws, u16* __restrict__ xpwd)
{
  int eb = blockIdx.x;
  if (eb < 2048)      conv_xt_body(eb*256 + threadIdx.x, xz, cw, cb, xc, xt);
  else if (eb < 6400) genWinv_body((eb - 2048)*256 + threadIdx.x, Winv);
  else if (eb < 6912) cvt16_body(eb - 6400, 256, threadIdx.x, ows, owd);
  else                cvt16_body(eb - 6912, 256, threadIdx.x, xpws, xpwd);
}

// ---------------- bf16 MFMA GEMM (templated tile, double-buffered) ----------
// C[m,n] = sum_k A[m,k0+k]*Bt[n,k0+k], k < K (per-split), row stride ldk.
// KS splits along K; split ks = bid/(gx*gy), k0 = ks*K.
// AUX blocks beyond KS*gx*gy:
//   1 = genWdft + cvt16 fus_w; 3 = cvt16 xconv->xcb;
//   5 = SECOND GEMM (x_dbc): blocks run the same MFMA body with runtime-
//       overridden operands (A=xga, B=xgb, K=2048, single col-tile) and an
//       f32 n<40 epilogue into xgc (ldc=40). Requires TM=128, TN=64.
// All aux work independent of this launch's GEMM + disjoint memory (audited).
// EPI: 0 plain f32; 3 spectral filter (bf16); 6 inv-DFT via LDS-transpose
//      (coalesced 16B stores into ycat[:,2048:]); 7 f32 split-K partial;
//      8 bf16 split-K partial.
// NOTE: operand-override locals named Aop/Bop — "B_" is a macro!
template<int TM, int TN, int EPI, int YCH, int AUX, int KS>
__global__ __launch_bounds__((TM/64)*(TN/32)*64) void mgemm_k(
    const u16* __restrict__ Ab, const u16* __restrict__ Bb,
    void* __restrict__ Cout, int K, int ldc,
    const float* __restrict__ aux0, u16* __restrict__ aux1,
    const float* __restrict__ aux2, const float* __restrict__ aux3,
    int gx, int gy,
    u16* __restrict__ gw,
    int ldk, const float* __restrict__ cvs, u16* __restrict__ cvd,
    const u16* __restrict__ xga, const u16* __restrict__ xgb,
    float* __restrict__ xgc)
{
  constexpr int WN   = TN/32;
  constexpr int NW   = (TM/64)*WN;
  constexpr int NTHR = NW*64;
  __shared__ __align__(16) u16 As[2][TM*64];
  __shared__ __align__(16) u16 Bs[2][TN*64];
  const int t = threadIdx.x;
  const int nwg = gx * gy;

  bool xg = false;
  int xgi = 0;
  if constexpr (AUX != 0) {
    int eb = (int)blockIdx.x - nwg*KS;
    if (eb >= 0) {
      if constexpr (AUX == 1) {              // genWdft (2176) + cvt fus_w (1024)
        if (eb < 2176) genWdft_body(eb*NTHR + t, gw);
        else           cvt16_body(eb - 2176, NTHR, t, cvs, cvd);
        return;
      } else if constexpr (AUX == 3) {       // cvt16 xconv -> xcb (1024)
        cvt16_body(eb, NTHR, t, cvs, cvd);
        return;
      } else {                               // 5: x_dbc sub-GEMM (16 blocks)
        xg = true; xgi = eb;
      }
    }
  }

  const int lane = t & 63;
  const int w = t >> 6;
  const int wm = w / WN, wn = w % WN;

  // operand setup: main GEMM (with split-K + XCD-chunked remap) or xg override
  const u16* Aop = Ab;
  const u16* Bop = Bb;
  int Kr = K, ldkr = ldk, k0 = 0;
  int M0, N0;
  if (xg) {
    Aop = xga; Bop = xgb; Kr = 2048; ldkr = 2048;
    M0 = xgi * TM; N0 = 0;
  } else {
    int bid = blockIdx.x;
    int ks = 0;
    if constexpr (KS > 1) { ks = bid / nwg; bid -= ks*nwg; }
    k0 = ks * K;
    const int lid = (bid & 7) * (nwg >> 3) + (bid >> 3);
    int bx, by;
    if (YCH) { by = lid / gx; bx = lid - by*gx; }
    else     { bx = lid / gy; by = lid - bx*gy; }
    M0 = by * TM; N0 = bx * TN;
    if constexpr (EPI == 7) {
      Cout = (void*)((float*)Cout + (size_t)ks * ((size_t)gy*TM*ldc));
    } else if constexpr (EPI == 8) {
      Cout = (void*)((u16*)Cout + (size_t)ks * ((size_t)gy*TM*ldc));
    }
  }

  f32x4 acc[4][2] = {};

  auto stage = [&](int buf, int kk0) {
    #pragma unroll
    for (int q = 0; q < TM*8/NTHR; q++) {
      int u = q*NTHR + t;
      int row = u >> 3, gpr = u & 7;
      int grp = gpr ^ (row & 7);        // XOR swizzle
      gload16(Aop + (size_t)(M0+row)*ldkr + k0 + kk0 + grp*8, &As[buf][u*8]);
    }
    #pragma unroll
    for (int q = 0; q < TN*8/NTHR; q++) {
      int u = q*NTHR + t;
      int row = u >> 3, gpr = u & 7;
      int grp = gpr ^ (row & 7);
      gload16(Bop + (size_t)(N0+row)*ldkr + k0 + kk0 + grp*8, &Bs[buf][u*8]);
    }
  };

  stage(0, 0);
  const int nk = Kr >> 6;
  for (int kst = 0; kst < nk; kst++) {
    const int buf = kst & 1;
    __syncthreads();                    // drain stage(buf); protect buf^1 overwrite
    if (kst + 1 < nk) stage(buf ^ 1, (kst + 1) << 6);
    const u16* Asb = As[buf];
    const u16* Bsb = Bs[buf];
    #pragma unroll
    for (int kk = 0; kk < 2; kk++) {
      const int quad = lane >> 4;
      const int grp = kk*4 + quad;
      short8 af[4], bfr[2];
      #pragma unroll
      for (int i = 0; i < 4; i++) {
        int row = wm*64 + i*16 + (lane & 15);
        af[i] = *(const short8*)&Asb[(row*8 + (grp ^ (row & 7)))*8];
      }
      #pragma unroll
      for (int j = 0; j < 2; j++) {
        int row = wn*32 + j*16 + (lane & 15);
        bfr[j] = *(const short8*)&Bsb[(row*8 + (grp ^ (row & 7)))*8];
      }
      #pragma unroll
      for (int i = 0; i < 4; i++)
        #pragma unroll
        for (int j = 0; j < 2; j++)
          acc[i][j] = mfma_bf16(af[i], bfr[j], acc[i][j]);
    }
  }

  if (xg) {
    // x_dbc epilogue: f32, n<40 only, row stride 40
    #pragma unroll
    for (int i = 0; i < 4; i++) {
      int mbase = M0 + wm*64 + i*16 + (lane >> 4)*4;
      #pragma unroll
      for (int j = 0; j < 2; j++) {
        int n = wn*32 + j*16 + (lane & 15);
        if (n < 40) {
          #pragma unroll
          for (int r = 0; r < 4; r++)
            xgc[(size_t)(mbase + r)*40 + n] = acc[i][j][r];
        }
      }
    }
    return;
  }

  if constexpr (EPI == 6) {
    // LDS-transpose epilogue: tile [c_loc 128][l_loc 64] -> coalesced 16B
    // stores into ycat[(b,l) row][2048 + c]. Pad 66 breaks bank aliasing.
    u16* T = (u16*)&As[0][0];           // 128*66*2 = 16.9KB <= 32KB As
    __syncthreads();                    // all waves done reading As
    #pragma unroll
    for (int i = 0; i < 4; i++) {
      int cb = wm*64 + i*16 + (lane >> 4)*4;
      #pragma unroll
      for (int j = 0; j < 2; j++) {
        int ll = wn*32 + j*16 + (lane & 15);
        #pragma unroll
        for (int r = 0; r < 4; r++)
          T[(cb + r)*66 + ll] = f2bf(acc[i][j][r]);
      }
    }
    __syncthreads();
    const int b2 = M0 >> 11, c0 = M0 & (INNER_-1);
    u16* yc = (u16*)Cout;
    #pragma unroll
    for (int q = 0; q < (TM*TN/8)/NTHR; q++) {
      int task = q*NTHR + t;
      int cg = task & 15, ll = task >> 4;
      union { u16 a[8]; short8 v8; } tu;
      #pragma unroll
      for (int e = 0; e < 8; e++) tu.a[e] = T[(cg*8 + e)*66 + ll];
      *(short8*)&yc[((size_t)((b2 << 10) + N0 + ll) << 12) + 2048 + c0 + cg*8] = tu.v8;
    }
  } else {
    // C/D layout: col = lane&15, row = (lane>>4)*4 + r
    #pragma unroll
    for (int i = 0; i < 4; i++) {
      int mbase = M0 + wm*64 + i*16 + (lane >> 4)*4;
      #pragma unroll
      for (int j = 0; j < 2; j++) {
        int n = N0 + wn*32 + j*16 + (lane & 15);
        #pragma unroll
        for (int r = 0; r < 4; r++) {
          int m = mbase + r;
          float v = acc[i][j][r];
          if (EPI == 0) {
            ((float*)Cout)[(size_t)m*ldc + n] = v;
          } else if (EPI == 3) {        // spectral filter, complex pair via shfl
            float pv = __shfl_xor(v, 1, 64);
            int f = n >> 1;
            float outv = 0.f;
            if (f < NFFT_) {
              int c = m & (INNER_-1);
              float d  = fexp_(-aux2[c] * (float)f * (1.f/512.f));
              float wr = aux0[c*NFFT_+f]*d, wi = aux3[c*NFFT_+f]*d;
              float a = (n & 1) ? pv : v;
              float b = (n & 1) ? v : pv;
              outv = (n & 1) ? (a*wi + b*wr) : (a*wr - b*wi);
            }
            ((u16*)Cout)[(size_t)m*ldc + n] = f2bf(outv);
          } else if (EPI == 7) {        // f32 split-K partial
            ((float*)Cout)[(size_t)m*ldc + n] = v;
          } else {                      // 8: bf16 split-K partial
            ((u16*)Cout)[(size_t)m*ldc + n] = f2bf(v);
          }
        }
      }
    }
  }
}

// ---------------- fusion combine: gate epilogue over bf16 partials ----------
__global__ __launch_bounds__(256) void combine_gate_k(
    const u16* __restrict__ P, const float* __restrict__ fus_b,
    const u16* __restrict__ ycat, const float* __restrict__ xz,
    u16* __restrict__ ycomb)
{
  int i4 = (blockIdx.x*256 + threadIdx.x)*4;   // m*2048 + n
  int m = i4 >> 11, n = i4 & 2047;
  ushort4 p0 = *(const ushort4*)(P + i4);
  ushort4 p1 = *(const ushort4*)(P + 4194304 + i4);
  ushort4 ysv = *(const ushort4*)(ycat + (size_t)m*4096 + n);
  ushort4 ypv = *(const ushort4*)(ycat + (size_t)m*4096 + 2048 + n);
  float4 zv = *(const float4*)(xz + (size_t)m*4096 + 2048 + n);
  float4 fb = *(const float4*)(fus_b + n);
  float pp[4] = {bf2f(p0.x)+bf2f(p1.x), bf2f(p0.y)+bf2f(p1.y),
                 bf2f(p0.z)+bf2f(p1.z), bf2f(p0.w)+bf2f(p1.w)};
  float zz[4] = {zv.x, zv.y, zv.z, zv.w};
  float bb[4] = {fb.x, fb.y, fb.z, fb.w};
  u16 ys[4] = {ysv.x, ysv.y, ysv.z, ysv.w};
  u16 yp[4] = {ypv.x, ypv.y, ypv.z, ypv.w};
  ushort4 o;
  u16* op = (u16*)&o;
  #pragma unroll
  for (int j = 0; j < 4; j++) {
    float g = fsigm_(pp[j] + bb[j]);
    op[j] = f2bf((g*bf2f(ys[j]) + (1.f-g)*bf2f(yp[j]))*fsilu_(zz[j]));
  }
  *(ushort4*)(ycomb + i4) = o;
}

// ---------------- SSM chunked scan (prefetched) ----------------
__global__ __launch_bounds__(256) void scan1_k(
    const float* __restrict__ xdbc, const float* __restrict__ xconv,
    const float* __restrict__ A_log, const float* __restrict__ dtw,
    const float* __restrict__ dtb, float* __restrict__ Pq)
{
  int idx = blockIdx.x*256 + threadIdx.x;   // (b*NCH+ch)*INNER + e
  int e  = idx & (INNER_-1);
  int bc = idx >> 11;
  int ch = bc & (NCH_-1);
  int b  = bc >> 5;
  float A[STATE_];
  #pragma unroll
  for (int s=0;s<STATE_;s++) A[s] = -fexp_(A_log[e*STATE_+s]);
  float w[DTR_];
  #pragma unroll
  for (int r=0;r<DTR_;r++) w[r] = dtw[e*DTR_+r];
  float bias = dtb[e];
  float h[STATE_] = {};
  float sdt = 0.f;
  int mbase = b*L_ + ch*CHL_;
  float dtx[DTR_], Bv[STATE_], xcv;
  {
    const float* row = xdbc + (size_t)mbase*40;
    #pragma unroll
    for (int r=0;r<DTR_;r++) dtx[r] = row[r];
    #pragma unroll
    for (int s=0;s<STATE_;s++) Bv[s] = row[8+s];
    xcv = xconv[(size_t)mbase*INNER_ + e];
  }
  for (int l=0;l<CHL_;l++) {
    float ndtx[DTR_], nBv[STATE_], nxcv = 0.f;
    if (l+1 < CHL_) {
      const float* nrow = xdbc + (size_t)(mbase+l+1)*40;
      #pragma unroll
      for (int r=0;r<DTR_;r++) ndtx[r] = nrow[r];
      #pragma unroll
      for (int s=0;s<STATE_;s++) nBv[s] = nrow[8+s];
      nxcv = xconv[(size_t)(mbase+l+1)*INNER_ + e];
    } else {
      #pragma unroll
      for (int r=0;r<DTR_;r++) ndtx[r] = 0.f;
      #pragma unroll
      for (int s=0;s<STATE_;s++) nBv[s] = 0.f;
    }
    float v = bias;
    #pragma unroll
    for (int r=0;r<DTR_;r++) v += dtx[r]*w[r];
    float dt = fsoftplus_(v);
    sdt += dt;
    float dx = dt * xcv;
    #pragma unroll
    for (int s=0;s<STATE_;s++) {
      float dA = fexp_(dt*A[s]);
      h[s] = dA*h[s] + dx*Bv[s];
    }
    #pragma unroll
    for (int r=0;r<DTR_;r++) dtx[r] = ndtx[r];
    #pragma unroll
    for (int s=0;s<STATE_;s++) Bv[s] = nBv[s];
    xcv = nxcv;
  }
  float* o = Pq + (size_t)idx*32;
  #pragma unroll
  for (int s=0;s<STATE_;s++) { o[s] = fexp_(A[s]*sdt); o[16+s] = h[s]; }
}

__global__ __launch_bounds__(256) void scan2_k(float* __restrict__ Pq)
{
  int idx = blockIdx.x*256 + threadIdx.x;   // 65536
  int s = idx & 15;
  int e = (idx >> 4) & (INNER_-1);
  int b = idx >> 15;
  float h = 0.f;
  for (int ch = 0; ch < NCH_; ch++) {
    size_t base = ((size_t)(b*NCH_+ch)*INNER_ + e)*32;
    float p = Pq[base + s];
    float q = Pq[base + 16 + s];
    Pq[base + 16 + s] = h;
    h = p*h + q;
  }
}

__global__ __launch_bounds__(256) void scan3_k(
    const float* __restrict__ xdbc, const float* __restrict__ xconv,
    const float* __restrict__ A_log, const float* __restrict__ dtw,
    const float* __restrict__ dtb, const float* __restrict__ Dp,
    const float* __restrict__ Pq, u16* __restrict__ ycat)
{
  int idx = blockIdx.x*256 + threadIdx.x;
  int e  = idx & (INNER_-1);
  int bc = idx >> 11;
  int ch = bc & (NCH_-1);
  int b  = bc >> 5;
  float A[STATE_];
  #pragma unroll
  for (int s=0;s<STATE_;s++) A[s] = -fexp_(A_log[e*STATE_+s]);
  float w[DTR_];
  #pragma unroll
  for (int r=0;r<DTR_;r++) w[r] = dtw[e*DTR_+r];
  float bias = dtb[e];
  float Dv = Dp[e];
  float h[STATE_];
  const float* hi = Pq + (size_t)idx*32 + 16;
  #pragma unroll
  for (int s=0;s<STATE_;s++) h[s] = hi[s];
  int mbase = b*L_ + ch*CHL_;
  float dtx[DTR_], Bv[STATE_], Cv[STATE_], xcv;
  {
    const float* row = xdbc + (size_t)mbase*40;
    #pragma unroll
    for (int r=0;r<DTR_;r++) dtx[r] = row[r];
    #pragma unroll
    for (int s=0;s<STATE_;s++) { Bv[s] = row[8+s]; Cv[s] = row[24+s]; }
    xcv = xconv[(size_t)mbase*INNER_ + e];
  }
  for (int l=0;l<CHL_;l++) {
    float ndtx[DTR_], nBv[STATE_], nCv[STATE_], nxcv = 0.f;
    if (l+1 < CHL_) {
      const float* nrow = xdbc + (size_t)(mbase+l+1)*40;
      #pragma unroll
      for (int r=0;r<DTR_;r++) ndtx[r] = nrow[r];
      #pragma unroll
      for (int s=0;s<STATE_;s++) { nBv[s] = nrow[8+s]; nCv[s] = nrow[24+s]; }
      nxcv = xconv[(size_t)(mbase+l+1)*INNER_ + e];
    } else {
      #pragma unroll
      for (int r=0;r<DTR_;r++) ndtx[r] = 0.f;
      #pragma unroll
      for (int s=0;s<STATE_;s++) { nBv[s] = 0.f; nCv[s] = 0.f; }
    }
    float v = bias;
    #pragma unroll
    for (int r=0;r<DTR_;r++) v += dtx[r]*w[r];
    float dt = fsoftplus_(v);
    float dx = dt * xcv;
    float y = 0.f;
    #pragma unroll
    for (int s=0;s<STATE_;s++) {
      float dA = fexp_(dt*A[s]);
      h[s] = dA*h[s] + dx*Bv[s];
      y += h[s]*Cv[s];
    }
    ycat[(size_t)(mbase+l)*4096 + e] = f2bf(y + xcv*Dv);
    #pragma unroll
    for (int r=0;r<DTR_;r++) dtx[r] = ndtx[r];
    #pragma unroll
    for (int s=0;s<STATE_;s++) { Bv[s] = nBv[s]; Cv[s] = nCv[s]; }
    xcv = nxcv;
  }
}

// ---------------- layernorm over summed out_proj partials + residual --------
__global__ __launch_bounds__(256) void ln2_k(const float* __restrict__ Q,
    const float* __restrict__ xres,
    const float* __restrict__ gma, const float* __restrict__ bta,
    float* __restrict__ out)
{
  int m = blockIdx.x;
  float s=0.f, s2=0.f;
  float v[4];
  #pragma unroll
  for (int j=0;j<4;j++) {
    int n = threadIdx.x + j*256;
    size_t idx = (size_t)m*DM_ + n;
    v[j] = Q[idx] + Q[2097152 + idx] + xres[idx];
    s += v[j]; s2 += v[j]*v[j];
  }
  #pragma unroll
  for (int off=32; off>=1; off>>=1) {
    s  += __shfl_down(s, off);
    s2 += __shfl_down(s2, off);
  }
  __shared__ float rs[4], rs2[4], stats[2];
  int wid = threadIdx.x >> 6;
  if ((threadIdx.x & 63) == 0) { rs[wid]=s; rs2[wid]=s2; }
  __syncthreads();
  if (threadIdx.x == 0) {
    float ts  = rs[0]+rs[1]+rs[2]+rs[3];
    float ts2 = rs2[0]+rs2[1]+rs2[2]+rs2[3];
    float mu  = ts/(float)DM_;
    float var = ts2/(float)DM_ - mu*mu;
    stats[0] = mu; stats[1] = rsqrtf(var + 1e-5f);
  }
  __syncthreads();
  float mu = stats[0], rstd = stats[1];
  #pragma unroll
  for (int j=0;j<4;j++) {
    int n = threadIdx.x + j*256;
    out[(size_t)m*DM_ + n] = (v[j]-mu)*rstd*gma[n] + bta[n];
  }
}

extern "C" void kernel_launch(void* const* d_in, const int* in_sizes, int n_in,
                              void* d_out, int out_size, void* d_ws, size_t ws_size,
                              hipStream_t stream)
{
  const float* x       = (const float*)d_in[0];
  const float* in_w    = (const float*)d_in[1];
  const float* conv_w  = (const float*)d_in[2];
  const float* conv_b  = (const float*)d_in[3];
  const float* A_log   = (const float*)d_in[4];
  const float* Dp      = (const float*)d_in[5];
  const float* xproj_w = (const float*)d_in[6];
  const float* dt_w    = (const float*)d_in[7];
  const float* dt_b    = (const float*)d_in[8];
  const float* f_re    = (const float*)d_in[9];
  const float* f_im    = (const float*)d_in[10];
  const float* s_dec   = (const float*)d_in[11];
  const float* fus_w   = (const float*)d_in[12];
  const float* fus_b   = (const float*)d_in[13];
  const float* out_w   = (const float*)d_in[14];
  const float* ln_g    = (const float*)d_in[15];
  const float* ln_b    = (const float*)d_in[16];
  float* out = (float*)d_out;

  // ---- workspace carve (fp32 region then bf16 region), ~137 MB total ----
  float* ws    = (float*)d_ws;
  float* xz    = ws;                       // 8388608  (M x 4096)
  float* xconv = xz    + 8388608;          // 4194304  (M x 2048)
  float* xdbc  = xconv + 4194304;          // 81920    (M x 40)
  float* Pq    = xdbc  + 81920;            // 4194304  (B*NCH*INNER x 32)
  u16* ub      = (u16*)(Pq + 4194304);
  u16* xb      = ub;                       // 2097152   x bf16; reused: Winv + xpwb
  u16* inwb    = xb    + 2097152;          // 4194304   in_w bf16; reused as xcb
  u16* fuswb   = inwb  + 4194304;          // 8388608   fus_w bf16 (L1 aux)
  u16* outwb   = fuswb + 8388608;          // 2097152   out_w bf16 (L2 aux)
  u16* xt      = outwb + 2097152;          // 4194304   x_inner^T bf16; reused as ycomb
  u16* Wb      = xt    + 4194304;          // 1114112   Wdft (NFP_ x 1024)
  u16* XFb     = Wb    + 1114112;          // 4456448   (MD x NFP_) bf16
  u16* ycat    = XFb   + 4456448;          // 8388608   (M x 4096) bf16
  u16* ycomb   = xt;
  u16* Winv    = xb;                       // 1114112; xb dead after L1
  u16* xpwb    = xb + 1114112;             // 40x2048 cvt'd; B-rows 40-63 read
                                           // leftover finite x-bf16 (no NaN)
  u16* xcb     = inwb;                     // 4194304 u16 (xconv bf16); inwb dead after L1
  u16* fpart   = (u16*)xconv;              // 8388608 u16 (dead after scan3)
  float* opart = Pq;                       // 4194304 f (dead after scan3)

  // 0. convert x + in_w to bf16
  cvt2_k<<<CVT2_NT/1024, 256, 0, stream>>>(x, in_w, xb);

  // 1. xz = x @ in_proj_w^T (2048 x 4096 x 1024), plain f32 epilogue
  //    + aux genWdft (2176) + aux cvt fus_w (1024)
  mgemm_k<128,128,0,0,1,1><<<512 + 2176 + 1024, 512, 0, stream>>>(
      xb, inwb, xz, 1024, 4096, nullptr, nullptr, nullptr, nullptr, 32, 16,
      Wb, 1024, fus_w, fuswb, nullptr, nullptr, nullptr);
  // 2. conv+silu (xconv) + x_inner^T emit (xt) + genWinv + cvt out_w + cvt xproj_w
  aux2_k<<<6932, 256, 0, stream>>>(xz, conv_w, conv_b, xconv, xt, Winv,
                                   out_w, outwb, xproj_w, xpwb);
  // 3. forward DFT + spectral filter: XFb = filt(xt @ Wdft)  [544 GEMM blocks]
  //    + aux cvt xconv -> xcb bf16 (1024 blocks)
  mgemm_k<128,64,3,1,3,1><<<544 + 1024, 256, 0, stream>>>(
      xt, Wb, XFb, 1024, NFP_, f_re, nullptr, s_dec, f_im, 17, 32,
      nullptr, 1024, xconv, xcb, nullptr, nullptr, nullptr);
  // 4. inverse DFT (4096 x 1024 x NFP_), LDS-transpose epilogue -> ycat[:,2048:]
  //    [512 GEMM blocks] + x_dbc sub-GEMM (16 blocks: xcb @ xpwb^T -> xdbc)
  mgemm_k<128,64,6,1,5,1><<<512 + 16, 256, 0, stream>>>(
      XFb, Winv, ycat, NFP_, 0, nullptr, nullptr, nullptr, nullptr, 16, 32,
      nullptr, NFP_, nullptr, nullptr, xcb, xpwb, xdbc);
  // 5-7. chunked SSM scan -> y_cat[:, :2048] (bf16)
  scan1_k<<<(B_*NCH_*INNER_)/256, 256, 0, stream>>>(xdbc, xconv, A_log, dt_w, dt_b, Pq);
  scan2_k<<<(B_*INNER_*STATE_)/256, 256, 0, stream>>>(Pq);
  scan3_k<<<(B_*NCH_*INNER_)/256, 256, 0, stream>>>(xdbc, xconv, A_log, dt_w, dt_b, Dp, Pq, ycat);
  // 8a. fusion GEMM split-K x2 (2048 x 2048 x 4096), bf16 partials -> fpart
  mgemm_k<128,128,8,0,0,2><<<2*256, 512, 0, stream>>>(
      ycat, fuswb, fpart, 2048, 2048, nullptr, nullptr, nullptr, nullptr, 16, 16,
      nullptr, 4096, nullptr, nullptr, nullptr, nullptr, nullptr);
  // 8b. combine partials + gate epilogue -> ycomb bf16
  combine_gate_k<<<(2048*2048/4)/256, 256, 0, stream>>>(
      fpart, fus_b, ycat, xz, ycomb);
  // 9. out proj split-K x2 (2048 x 1024 x 2048) -> f32 partials in opart
  mgemm_k<64,64,7,1,0,2><<<2*512, 128, 0, stream>>>(
      ycomb, outwb, opart, 1024, 1024, nullptr, nullptr, nullptr, nullptr, 16, 32,
      nullptr, 2048, nullptr, nullptr, nullptr, nullptr, nullptr);
  // 10. layernorm over (partial0 + partial1 + residual) -> d_out
  ln2_k<<<M_, 256, 0, stream>>>(opart, x, ln_g, ln_b, out);
}

// Round 11
// 368.038 us; speedup vs baseline: 1.0843x; 1.0015x over previous
//
#include <hip/hip_runtime.h>
#include <math.h>

#define B_ 2
#define L_ 1024
#define DM_ 1024
#define STATE_ 16
#define CONV_ 4
#define DTR_ 8
#define INNER_ 2048
#define M_ (B_*L_)        /* 2048 rows (b,l) */
#define MD_ (B_*INNER_)   /* 4096 rows (b,c) */
#define NFFT_ 513
#define NFP_ 1088         /* 2*513=1026 padded to 17*64 */
#define NCH_ 32
#define CHL_ 32

typedef unsigned short u16;
typedef __attribute__((ext_vector_type(8))) short short8;
typedef __attribute__((ext_vector_type(8))) __bf16 bf16x8;
typedef __attribute__((ext_vector_type(4))) float f32x4;

__device__ __forceinline__ float frcp_(float x) { return __builtin_amdgcn_rcpf(x); }
__device__ __forceinline__ float fexp_(float x) { return __expf(x); }
__device__ __forceinline__ float fsigm_(float x) { return frcp_(1.f + __expf(-x)); }
__device__ __forceinline__ float fsilu_(float x) { return x * frcp_(1.f + __expf(-x)); }
__device__ __forceinline__ float fsoftplus_(float v) {
  return (v > 20.f) ? v : __logf(1.f + __expf(v));
}
__device__ __forceinline__ u16 f2bf(float f) {
  union { float f; unsigned u; } v; v.f = f;
  unsigned r = v.u + 0x7fffu + ((v.u >> 16) & 1u);
  return (u16)(r >> 16);
}
__device__ __forceinline__ float bf2f(u16 h) {
  union { unsigned u; float f; } v; v.u = ((unsigned)h) << 16;
  return v.f;
}
__device__ __forceinline__ void gload16(const void* g, void* l) {
  __builtin_amdgcn_global_load_lds(
      (const __attribute__((address_space(1))) unsigned*)g,
      (__attribute__((address_space(3))) unsigned*)l, 16, 0, 0);
}
__device__ __forceinline__ f32x4 mfma_bf16(short8 a, short8 b, f32x4 c) {
  return __builtin_amdgcn_mfma_f32_16x16x32_bf16(
      __builtin_bit_cast(bf16x8, a), __builtin_bit_cast(bf16x8, b), c, 0, 0, 0);
}

// ---------------- aux bodies ------------------------------------------------
// 16 contiguous floats per thread -> bf16
__device__ __forceinline__ void cvt16_body(int eb, int nthr, int t,
    const float* __restrict__ src, u16* __restrict__ dst)
{
  int i = (eb*nthr + t)*16;
  #pragma unroll
  for (int q = 0; q < 4; q++) {
    float4 v = *(const float4*)(src + i + q*4);
    ushort4 o;
    o.x = f2bf(v.x); o.y = f2bf(v.y); o.z = f2bf(v.z); o.w = f2bf(v.w);
    *(ushort4*)(dst + i + q*4) = o;
  }
}

// DFT matrix (bf16, K-contiguous): W[col*1024 + l], col < NFP_
__device__ __forceinline__ void genWdft_body(int idx, u16* __restrict__ W)
{
  int l = idx & (L_-1);
  int col = idx >> 10;
  float v = 0.f;
  int f = col >> 1;
  if (f < NFFT_) {
    int ph = (l*f) & (L_-1);
    float th = (float)ph * (6.283185307179586f / (float)L_);
    v = (col & 1) ? -__sinf(th) : __cosf(th);
  }
  W[idx] = f2bf(v);
}

// inverse-DFT matrix: W[l*NFP_ + r], l < 1024, r < NFP_
__device__ __forceinline__ void genWinv_body(int idx, u16* __restrict__ W)
{
  int r = idx % NFP_;
  int l = idx / NFP_;
  int f = r >> 1;
  float v = 0.f;
  if (f < NFFT_) {
    bool edge = (f == 0) || (f == 512);
    float sc = (edge ? 1.f : 2.f) / (float)L_;
    int ph = (f*l) & (L_-1);
    float th = (float)ph * (6.283185307179586f / (float)L_);
    if (r & 1) v = edge ? 0.f : -sc*__sinf(th);
    else       v = sc*__cosf(th);
  }
  W[idx] = f2bf(v);
}

// depthwise causal conv(4) + silu, 8 l per thread; ALSO emits x_inner^T bf16
// (pre-conv values) coalesced into xt[b*2048+c][l] for the DFT GEMM.
__device__ __forceinline__ void conv_xt_body(int idx, const float* __restrict__ xz,
    const float* __restrict__ cw, const float* __restrict__ cb,
    float* __restrict__ xc, u16* __restrict__ xt)
{
  int c = idx & (INNER_-1);
  int g = idx >> 11;                        // 0..255
  int b = g >> 7;
  int lb = (g & 127) * 8;
  float w0=cw[c*4+0], w1=cw[c*4+1], w2=cw[c*4+2], w3=cw[c*4+3];
  float bias = cb[c];
  float v[11];
  #pragma unroll
  for (int j = 0; j < 11; j++) {
    int l = lb - 3 + j;
    v[j] = (l >= 0) ? xz[((size_t)((b << 10) + l))*4096 + c] : 0.f;
  }
  union { u16 a[8]; short8 v8; } tu;
  #pragma unroll
  for (int j = 0; j < 8; j++) tu.a[j] = f2bf(v[j+3]);
  *(short8*)&xt[(((size_t)(b*INNER_ + c)) << 10) + lb] = tu.v8;
  #pragma unroll
  for (int j = 0; j < 8; j++) {
    float s = bias + w0*v[j] + w1*v[j+1] + w2*v[j+2] + w3*v[j+3];
    xc[((size_t)((b << 10) + lb + j))*INNER_ + c] = fsilu_(s);
  }
}

// ---------------- launch 0: cvt x + in_w, genWdft, cvt fus_w (no LDS) -------
// eb < 6144: cvt x (2.1M f) + in_w (4.2M f), 4 floats/thread
// eb < 10496: genWdft (NFP_*1024 elems, 256/block)
// else: cvt fus_w (8.4M f, 4096/block)
#define CVT2_N0 2097152
__global__ __launch_bounds__(256) void cvt3_k(
    const float* __restrict__ s0, const float* __restrict__ s1,
    u16* __restrict__ out, u16* __restrict__ Wd,
    const float* __restrict__ fws, u16* __restrict__ fwd)
{
  int eb = blockIdx.x;
  if (eb < 6144) {
    int i = (eb*256 + threadIdx.x) * 4;
    const float* src; int off;
    if (i < CVT2_N0) { src = s0; off = 0; }
    else             { src = s1; off = CVT2_N0; }
    float4 v = *(const float4*)(src + (i - off));
    ushort4 o;
    o.x = f2bf(v.x); o.y = f2bf(v.y); o.z = f2bf(v.z); o.w = f2bf(v.w);
    *(ushort4*)(out + i) = o;
  } else if (eb < 10496) {
    genWdft_body((eb - 6144)*256 + threadIdx.x, Wd);
  } else {
    cvt16_body(eb - 10496, 256, threadIdx.x, fws, fwd);
  }
}

// ---------------- standalone aux launch: conv+xt, genWinv, cvts -------------
__global__ __launch_bounds__(256) void aux2_k(
    const float* __restrict__ xz, const float* __restrict__ cw,
    const float* __restrict__ cb, float* __restrict__ xc,
    u16* __restrict__ xt, u16* __restrict__ Winv,
    const float* __restrict__ ows, u16* __restrict__ owd,
    const float* __restrict__ xpws, u16* __restrict__ xpwd)
{
  int eb = blockIdx.x;
  if (eb < 2048)      conv_xt_body(eb*256 + threadIdx.x, xz, cw, cb, xc, xt);
  else if (eb < 6400) genWinv_body((eb - 2048)*256 + threadIdx.x, Winv);
  else if (eb < 6912) cvt16_body(eb - 6400, 256, threadIdx.x, ows, owd);
  else                cvt16_body(eb - 6912, 256, threadIdx.x, xpws, xpwd);
}

// ---------------- bf16 MFMA GEMM (templated tile, double-buffered) ----------
// C[m,n] = sum_k A[m,k0+k]*Bt[n,k0+k], k < K (per-split), row stride ldk.
// KS splits along K; split ks = bid/(gx*gy), k0 = ks*K.
// AUX blocks beyond KS*gx*gy:
//   3 = cvt16 xconv->xcb;
//   5 = SECOND GEMM (x_dbc): blocks run the same MFMA body with runtime-
//       overridden operands (A=xga, B=xgb, K=2048, single col-tile) and an
//       f32 n<40 epilogue into xgc (ldc=40). Requires TM=128, TN=64.
// All aux work independent of this launch's GEMM + disjoint memory (audited).
// EPI: 0 plain f32; 3 spectral filter (bf16); 6 inv-DFT via LDS-transpose
//      (coalesced 16B stores into ycat[:,2048:]); 7 f32 split-K partial;
//      8 bf16 split-K partial.
// NOTE: operand-override locals named Aop/Bop — "B_" is a macro!
template<int TM, int TN, int EPI, int YCH, int AUX, int KS>
__global__ __launch_bounds__((TM/64)*(TN/32)*64) void mgemm_k(
    const u16* __restrict__ Ab, const u16* __restrict__ Bb,
    void* __restrict__ Cout, int K, int ldc,
    const float* __restrict__ aux0, u16* __restrict__ aux1,
    const float* __restrict__ aux2, const float* __restrict__ aux3,
    int gx, int gy,
    int ldk, const float* __restrict__ cvs, u16* __restrict__ cvd,
    const u16* __restrict__ xga, const u16* __restrict__ xgb,
    float* __restrict__ xgc)
{
  constexpr int WN   = TN/32;
  constexpr int NW   = (TM/64)*WN;
  constexpr int NTHR = NW*64;
  __shared__ __align__(16) u16 As[2][TM*64];
  __shared__ __align__(16) u16 Bs[2][TN*64];
  const int t = threadIdx.x;
  const int nwg = gx * gy;

  bool xg = false;
  int xgi = 0;
  if constexpr (AUX != 0) {
    int eb = (int)blockIdx.x - nwg*KS;
    if (eb >= 0) {
      if constexpr (AUX == 3) {              // cvt16 xconv -> xcb (1024)
        cvt16_body(eb, NTHR, t, cvs, cvd);
        return;
      } else {                               // 5: x_dbc sub-GEMM (16 blocks)
        xg = true; xgi = eb;
      }
    }
  }

  const int lane = t & 63;
  const int w = t >> 6;
  const int wm = w / WN, wn = w % WN;

  // operand setup: main GEMM (with split-K + XCD-chunked remap) or xg override
  const u16* Aop = Ab;
  const u16* Bop = Bb;
  int Kr = K, ldkr = ldk, k0 = 0;
  int M0, N0;
  if (xg) {
    Aop = xga; Bop = xgb; Kr = 2048; ldkr = 2048;
    M0 = xgi * TM; N0 = 0;
  } else {
    int bid = blockIdx.x;
    int ks = 0;
    if constexpr (KS > 1) { ks = bid / nwg; bid -= ks*nwg; }
    k0 = ks * K;
    const int lid = (bid & 7) * (nwg >> 3) + (bid >> 3);
    int bx, by;
    if (YCH) { by = lid / gx; bx = lid - by*gx; }
    else     { bx = lid / gy; by = lid - bx*gy; }
    M0 = by * TM; N0 = bx * TN;
    if constexpr (EPI == 7) {
      Cout = (void*)((float*)Cout + (size_t)ks * ((size_t)gy*TM*ldc));
    } else if constexpr (EPI == 8) {
      Cout = (void*)((u16*)Cout + (size_t)ks * ((size_t)gy*TM*ldc));
    }
  }

  f32x4 acc[4][2] = {};

  auto stage = [&](int buf, int kk0) {
    #pragma unroll
    for (int q = 0; q < TM*8/NTHR; q++) {
      int u = q*NTHR + t;
      int row = u >> 3, gpr = u & 7;
      int grp = gpr ^ (row & 7);        // XOR swizzle
      gload16(Aop + (size_t)(M0+row)*ldkr + k0 + kk0 + grp*8, &As[buf][u*8]);
    }
    #pragma unroll
    for (int q = 0; q < TN*8/NTHR; q++) {
      int u = q*NTHR + t;
      int row = u >> 3, gpr = u & 7;
      int grp = gpr ^ (row & 7);
      gload16(Bop + (size_t)(N0+row)*ldkr + k0 + kk0 + grp*8, &Bs[buf][u*8]);
    }
  };

  stage(0, 0);
  const int nk = Kr >> 6;
  for (int kst = 0; kst < nk; kst++) {
    const int buf = kst & 1;
    __syncthreads();                    // drain stage(buf); protect buf^1 overwrite
    if (kst + 1 < nk) stage(buf ^ 1, (kst + 1) << 6);
    const u16* Asb = As[buf];
    const u16* Bsb = Bs[buf];
    #pragma unroll
    for (int kk = 0; kk < 2; kk++) {
      const int quad = lane >> 4;
      const int grp = kk*4 + quad;
      short8 af[4], bfr[2];
      #pragma unroll
      for (int i = 0; i < 4; i++) {
        int row = wm*64 + i*16 + (lane & 15);
        af[i] = *(const short8*)&Asb[(row*8 + (grp ^ (row & 7)))*8];
      }
      #pragma unroll
      for (int j = 0; j < 2; j++) {
        int row = wn*32 + j*16 + (lane & 15);
        bfr[j] = *(const short8*)&Bsb[(row*8 + (grp ^ (row & 7)))*8];
      }
      #pragma unroll
      for (int i = 0; i < 4; i++)
        #pragma unroll
        for (int j = 0; j < 2; j++)
          acc[i][j] = mfma_bf16(af[i], bfr[j], acc[i][j]);
    }
  }

  if (xg) {
    // x_dbc epilogue: f32, n<40 only, row stride 40
    #pragma unroll
    for (int i = 0; i < 4; i++) {
      int mbase = M0 + wm*64 + i*16 + (lane >> 4)*4;
      #pragma unroll
      for (int j = 0; j < 2; j++) {
        int n = wn*32 + j*16 + (lane & 15);
        if (n < 40) {
          #pragma unroll
          for (int r = 0; r < 4; r++)
            xgc[(size_t)(mbase + r)*40 + n] = acc[i][j][r];
        }
      }
    }
    return;
  }

  if constexpr (EPI == 6) {
    // LDS-transpose epilogue: tile [c_loc 128][l_loc 64] -> coalesced 16B
    // stores into ycat[(b,l) row][2048 + c]. Pad 66 breaks bank aliasing.
    u16* T = (u16*)&As[0][0];           // 128*66*2 = 16.9KB <= 32KB As
    __syncthreads();                    // all waves done reading As
    #pragma unroll
    for (int i = 0; i < 4; i++) {
      int cb = wm*64 + i*16 + (lane >> 4)*4;
      #pragma unroll
      for (int j = 0; j < 2; j++) {
        int ll = wn*32 + j*16 + (lane & 15);
        #pragma unroll
        for (int r = 0; r < 4; r++)
          T[(cb + r)*66 + ll] = f2bf(acc[i][j][r]);
      }
    }
    __syncthreads();
    const int b2 = M0 >> 11, c0 = M0 & (INNER_-1);
    u16* yc = (u16*)Cout;
    #pragma unroll
    for (int q = 0; q < (TM*TN/8)/NTHR; q++) {
      int task = q*NTHR + t;
      int cg = task & 15, ll = task >> 4;
      union { u16 a[8]; short8 v8; } tu;
      #pragma unroll
      for (int e = 0; e < 8; e++) tu.a[e] = T[(cg*8 + e)*66 + ll];
      *(short8*)&yc[((size_t)((b2 << 10) + N0 + ll) << 12) + 2048 + c0 + cg*8] = tu.v8;
    }
  } else {
    // C/D layout: col = lane&15, row = (lane>>4)*4 + r
    #pragma unroll
    for (int i = 0; i < 4; i++) {
      int mbase = M0 + wm*64 + i*16 + (lane >> 4)*4;
      #pragma unroll
      for (int j = 0; j < 2; j++) {
        int n = N0 + wn*32 + j*16 + (lane & 15);
        #pragma unroll
        for (int r = 0; r < 4; r++) {
          int m = mbase + r;
          float v = acc[i][j][r];
          if (EPI == 0) {
            ((float*)Cout)[(size_t)m*ldc + n] = v;
          } else if (EPI == 3) {        // spectral filter, complex pair via shfl
            float pv = __shfl_xor(v, 1, 64);
            int f = n >> 1;
            float outv = 0.f;
            if (f < NFFT_) {
              int c = m & (INNER_-1);
              float d  = fexp_(-aux2[c] * (float)f * (1.f/512.f));
              float wr = aux0[c*NFFT_+f]*d, wi = aux3[c*NFFT_+f]*d;
              float a = (n & 1) ? pv : v;
              float b = (n & 1) ? v : pv;
              outv = (n & 1) ? (a*wi + b*wr) : (a*wr - b*wi);
            }
            ((u16*)Cout)[(size_t)m*ldc + n] = f2bf(outv);
          } else if (EPI == 7) {        // f32 split-K partial
            ((float*)Cout)[(size_t)m*ldc + n] = v;
          } else {                      // 8: bf16 split-K partial
            ((u16*)Cout)[(size_t)m*ldc + n] = f2bf(v);
          }
        }
      }
    }
  }
}

// ---------------- fusion combine: gate epilogue over bf16 partials ----------
__global__ __launch_bounds__(256) void combine_gate_k(
    const u16* __restrict__ P, const float* __restrict__ fus_b,
    const u16* __restrict__ ycat, const float* __restrict__ xz,
    u16* __restrict__ ycomb)
{
  int i4 = (blockIdx.x*256 + threadIdx.x)*4;   // m*2048 + n
  int m = i4 >> 11, n = i4 & 2047;
  ushort4 p0 = *(const ushort4*)(P + i4);
  ushort4 p1 = *(const ushort4*)(P + 4194304 + i4);
  ushort4 ysv = *(const ushort4*)(ycat + (size_t)m*4096 + n);
  ushort4 ypv = *(const ushort4*)(ycat + (size_t)m*4096 + 2048 + n);
  float4 zv = *(const float4*)(xz + (size_t)m*4096 + 2048 + n);
  float4 fb = *(const float4*)(fus_b + n);
  float pp[4] = {bf2f(p0.x)+bf2f(p1.x), bf2f(p0.y)+bf2f(p1.y),
                 bf2f(p0.z)+bf2f(p1.z), bf2f(p0.w)+bf2f(p1.w)};
  float zz[4] = {zv.x, zv.y, zv.z, zv.w};
  float bb[4] = {fb.x, fb.y, fb.z, fb.w};
  u16 ys[4] = {ysv.x, ysv.y, ysv.z, ysv.w};
  u16 yp[4] = {ypv.x, ypv.y, ypv.z, ypv.w};
  ushort4 o;
  u16* op = (u16*)&o;
  #pragma unroll
  for (int j = 0; j < 4; j++) {
    float g = fsigm_(pp[j] + bb[j]);
    op[j] = f2bf((g*bf2f(ys[j]) + (1.f-g)*bf2f(yp[j]))*fsilu_(zz[j]));
  }
  *(ushort4*)(ycomb + i4) = o;
}

// ---------------- SSM chunked scan (prefetched) ----------------
__global__ __launch_bounds__(256) void scan1_k(
    const float* __restrict__ xdbc, const float* __restrict__ xconv,
    const float* __restrict__ A_log, const float* __restrict__ dtw,
    const float* __restrict__ dtb, float* __restrict__ Pq)
{
  int idx = blockIdx.x*256 + threadIdx.x;   // (b*NCH+ch)*INNER + e
  int e  = idx & (INNER_-1);
  int bc = idx >> 11;
  int ch = bc & (NCH_-1);
  int b  = bc >> 5;
  float A[STATE_];
  #pragma unroll
  for (int s=0;s<STATE_;s++) A[s] = -fexp_(A_log[e*STATE_+s]);
  float w[DTR_];
  #pragma unroll
  for (int r=0;r<DTR_;r++) w[r] = dtw[e*DTR_+r];
  float bias = dtb[e];
  float h[STATE_] = {};
  float sdt = 0.f;
  int mbase = b*L_ + ch*CHL_;
  float dtx[DTR_], Bv[STATE_], xcv;
  {
    const float* row = xdbc + (size_t)mbase*40;
    #pragma unroll
    for (int r=0;r<DTR_;r++) dtx[r] = row[r];
    #pragma unroll
    for (int s=0;s<STATE_;s++) Bv[s] = row[8+s];
    xcv = xconv[(size_t)mbase*INNER_ + e];
  }
  for (int l=0;l<CHL_;l++) {
    float ndtx[DTR_], nBv[STATE_], nxcv = 0.f;
    if (l+1 < CHL_) {
      const float* nrow = xdbc + (size_t)(mbase+l+1)*40;
      #pragma unroll
      for (int r=0;r<DTR_;r++) ndtx[r] = nrow[r];
      #pragma unroll
      for (int s=0;s<STATE_;s++) nBv[s] = nrow[8+s];
      nxcv = xconv[(size_t)(mbase+l+1)*INNER_ + e];
    } else {
      #pragma unroll
      for (int r=0;r<DTR_;r++) ndtx[r] = 0.f;
      #pragma unroll
      for (int s=0;s<STATE_;s++) nBv[s] = 0.f;
    }
    float v = bias;
    #pragma unroll
    for (int r=0;r<DTR_;r++) v += dtx[r]*w[r];
    float dt = fsoftplus_(v);
    sdt += dt;
    float dx = dt * xcv;
    #pragma unroll
    for (int s=0;s<STATE_;s++) {
      float dA = fexp_(dt*A[s]);
      h[s] = dA*h[s] + dx*Bv[s];
    }
    #pragma unroll
    for (int r=0;r<DTR_;r++) dtx[r] = ndtx[r];
    #pragma unroll
    for (int s=0;s<STATE_;s++) Bv[s] = nBv[s];
    xcv = nxcv;
  }
  float* o = Pq + (size_t)idx*32;
  #pragma unroll
  for (int s=0;s<STATE_;s++) { o[s] = fexp_(A[s]*sdt); o[16+s] = h[s]; }
}

__global__ __launch_bounds__(256) void scan2_k(float* __restrict__ Pq)
{
  int idx = blockIdx.x*256 + threadIdx.x;   // 65536
  int s = idx & 15;
  int e = (idx >> 4) & (INNER_-1);
  int b = idx >> 15;
  float h = 0.f;
  for (int ch = 0; ch < NCH_; ch++) {
    size_t base = ((size_t)(b*NCH_+ch)*INNER_ + e)*32;
    float p = Pq[base + s];
    float q = Pq[base + 16 + s];
    Pq[base + 16 + s] = h;
    h = p*h + q;
  }
}

__global__ __launch_bounds__(256) void scan3_k(
    const float* __restrict__ xdbc, const float* __restrict__ xconv,
    const float* __restrict__ A_log, const float* __restrict__ dtw,
    const float* __restrict__ dtb, const float* __restrict__ Dp,
    const float* __restrict__ Pq, u16* __restrict__ ycat)
{
  int idx = blockIdx.x*256 + threadIdx.x;
  int e  = idx & (INNER_-1);
  int bc = idx >> 11;
  int ch = bc & (NCH_-1);
  int b  = bc >> 5;
  float A[STATE_];
  #pragma unroll
  for (int s=0;s<STATE_;s++) A[s] = -fexp_(A_log[e*STATE_+s]);
  float w[DTR_];
  #pragma unroll
  for (int r=0;r<DTR_;r++) w[r] = dtw[e*DTR_+r];
  float bias = dtb[e];
  float Dv = Dp[e];
  float h[STATE_];
  const float* hi = Pq + (size_t)idx*32 + 16;
  #pragma unroll
  for (int s=0;s<STATE_;s++) h[s] = hi[s];
  int mbase = b*L_ + ch*CHL_;
  float dtx[DTR_], Bv[STATE_], Cv[STATE_], xcv;
  {
    const float* row = xdbc + (size_t)mbase*40;
    #pragma unroll
    for (int r=0;r<DTR_;r++) dtx[r] = row[r];
    #pragma unroll
    for (int s=0;s<STATE_;s++) { Bv[s] = row[8+s]; Cv[s] = row[24+s]; }
    xcv = xconv[(size_t)mbase*INNER_ + e];
  }
  for (int l=0;l<CHL_;l++) {
    float ndtx[DTR_], nBv[STATE_], nCv[STATE_], nxcv = 0.f;
    if (l+1 < CHL_) {
      const float* nrow = xdbc + (size_t)(mbase+l+1)*40;
      #pragma unroll
      for (int r=0;r<DTR_;r++) ndtx[r] = nrow[r];
      #pragma unroll
      for (int s=0;s<STATE_;s++) { nBv[s] = nrow[8+s]; nCv[s] = nrow[24+s]; }
      nxcv = xconv[(size_t)(mbase+l+1)*INNER_ + e];
    } else {
      #pragma unroll
      for (int r=0;r<DTR_;r++) ndtx[r] = 0.f;
      #pragma unroll
      for (int s=0;s<STATE_;s++) { nBv[s] = 0.f; nCv[s] = 0.f; }
    }
    float v = bias;
    #pragma unroll
    for (int r=0;r<DTR_;r++) v += dtx[r]*w[r];
    float dt = fsoftplus_(v);
    float dx = dt * xcv;
    float y = 0.f;
    #pragma unroll
    for (int s=0;s<STATE_;s++) {
      float dA = fexp_(dt*A[s]);
      h[s] = dA*h[s] + dx*Bv[s];
      y += h[s]*Cv[s];
    }
    ycat[(size_t)(mbase+l)*4096 + e] = f2bf(y + xcv*Dv);
    #pragma unroll
    for (int r=0;r<DTR_;r++) dtx[r] = ndtx[r];
    #pragma unroll
    for (int s=0;s<STATE_;s++) { Bv[s] = nBv[s]; Cv[s] = nCv[s]; }
    xcv = nxcv;
  }
}

// ---------------- layernorm over 4 out_proj partials + residual -------------
__global__ __launch_bounds__(256) void ln4_k(const float* __restrict__ Q,
    const float* __restrict__ xres,
    const float* __restrict__ gma, const float* __restrict__ bta,
    float* __restrict__ out)
{
  int m = blockIdx.x;
  float s=0.f, s2=0.f;
  float v[4];
  #pragma unroll
  for (int j=0;j<4;j++) {
    int n = threadIdx.x + j*256;
    size_t idx = (size_t)m*DM_ + n;
    v[j] = Q[idx] + Q[2097152 + idx] + Q[2*2097152 + idx] + Q[3*2097152 + idx]
         + xres[idx];
    s += v[j]; s2 += v[j]*v[j];
  }
  #pragma unroll
  for (int off=32; off>=1; off>>=1) {
    s  += __shfl_down(s, off);
    s2 += __shfl_down(s2, off);
  }
  __shared__ float rs[4], rs2[4], stats[2];
  int wid = threadIdx.x >> 6;
  if ((threadIdx.x & 63) == 0) { rs[wid]=s; rs2[wid]=s2; }
  __syncthreads();
  if (threadIdx.x == 0) {
    float ts  = rs[0]+rs[1]+rs[2]+rs[3];
    float ts2 = rs2[0]+rs2[1]+rs2[2]+rs2[3];
    float mu  = ts/(float)DM_;
    float var = ts2/(float)DM_ - mu*mu;
    stats[0] = mu; stats[1] = rsqrtf(var + 1e-5f);
  }
  __syncthreads();
  float mu = stats[0], rstd = stats[1];
  #pragma unroll
  for (int j=0;j<4;j++) {
    int n = threadIdx.x + j*256;
    out[(size_t)m*DM_ + n] = (v[j]-mu)*rstd*gma[n] + bta[n];
  }
}

extern "C" void kernel_launch(void* const* d_in, const int* in_sizes, int n_in,
                              void* d_out, int out_size, void* d_ws, size_t ws_size,
                              hipStream_t stream)
{
  const float* x       = (const float*)d_in[0];
  const float* in_w    = (const float*)d_in[1];
  const float* conv_w  = (const float*)d_in[2];
  const float* conv_b  = (const float*)d_in[3];
  const float* A_log   = (const float*)d_in[4];
  const float* Dp      = (const float*)d_in[5];
  const float* xproj_w = (const float*)d_in[6];
  const float* dt_w    = (const float*)d_in[7];
  const float* dt_b    = (const float*)d_in[8];
  const float* f_re    = (const float*)d_in[9];
  const float* f_im    = (const float*)d_in[10];
  const float* s_dec   = (const float*)d_in[11];
  const float* fus_w   = (const float*)d_in[12];
  const float* fus_b   = (const float*)d_in[13];
  const float* out_w   = (const float*)d_in[14];
  const float* ln_g    = (const float*)d_in[15];
  const float* ln_b    = (const float*)d_in[16];
  float* out = (float*)d_out;

  // ---- workspace carve (fp32 region then bf16 region), ~137 MB total ----
  float* ws    = (float*)d_ws;
  float* xz    = ws;                       // 8388608  (M x 4096)
  float* xconv = xz    + 8388608;          // 4194304  (M x 2048)
  float* xdbc  = xconv + 4194304;          // 81920    (M x 40)
  float* Pq    = xdbc  + 81920;            // 4194304  (B*NCH*INNER x 32)
  u16* ub      = (u16*)(Pq + 4194304);
  u16* xb      = ub;                       // 2097152   x bf16; reused: Winv + xpwb
  u16* inwb    = xb    + 2097152;          // 4194304   in_w bf16; reused as xcb
  u16* fuswb   = inwb  + 4194304;          // 8388608   fus_w bf16 (cvt3 aux)
  u16* outwb   = fuswb + 8388608;          // 2097152   out_w bf16 (aux2)
  u16* xt      = outwb + 2097152;          // 4194304   x_inner^T bf16; reused as ycomb
  u16* Wb      = xt    + 4194304;          // 1114112   Wdft (NFP_ x 1024)
  u16* XFb     = Wb    + 1114112;          // 4456448   (MD x NFP_) bf16
  u16* ycat    = XFb   + 4456448;          // 8388608   (M x 4096) bf16
  u16* ycomb   = xt;
  u16* Winv    = xb;                       // 1114112; xb dead after L1
  u16* xpwb    = xb + 1114112;             // 40x2048 cvt'd; B-rows 40-63 read
                                           // leftover finite x-bf16 (no NaN)
  u16* xcb     = inwb;                     // 4194304 u16 (xconv bf16); inwb dead after L1
  u16* fpart   = (u16*)xconv;              // 8388608 u16 (dead after scan3)
  // out_proj split-K x4 partials: 4 x 2048x1024 f32 = 8388608 f over the
  // contiguous dead span [xconv, xdbc, Pq] = 8470528 f (all dead after
  // combine_gate/scan3 have run).
  float* opart = xconv;

  // 0. cvt x+in_w (6144) + genWdft (4352) + cvt fus_w (2048) — no-LDS launch
  cvt3_k<<<12544, 256, 0, stream>>>(x, in_w, xb, Wb, fus_w, fuswb);

  // 1. xz = x @ in_proj_w^T (2048 x 4096 x 1024), pure GEMM (512 blocks)
  mgemm_k<128,128,0,0,0,1><<<512, 512, 0, stream>>>(
      xb, inwb, xz, 1024, 4096, nullptr, nullptr, nullptr, nullptr, 32, 16,
      1024, nullptr, nullptr, nullptr, nullptr, nullptr);
  // 2. conv+silu (xconv) + x_inner^T emit (xt) + genWinv + cvt out_w + cvt xproj_w
  aux2_k<<<6932, 256, 0, stream>>>(xz, conv_w, conv_b, xconv, xt, Winv,
                                   out_w, outwb, xproj_w, xpwb);
  // 3. forward DFT + spectral filter: XFb = filt(xt @ Wdft)  [544 GEMM blocks]
  //    + aux cvt xconv -> xcb bf16 (1024 blocks)
  mgemm_k<128,64,3,1,3,1><<<544 + 1024, 256, 0, stream>>>(
      xt, Wb, XFb, 1024, NFP_, f_re, nullptr, s_dec, f_im, 17, 32,
      1024, xconv, xcb, nullptr, nullptr, nullptr);
  // 4. inverse DFT (4096 x 1024 x NFP_), LDS-transpose epilogue -> ycat[:,2048:]
  //    [512 GEMM blocks] + x_dbc sub-GEMM (16 blocks: xcb @ xpwb^T -> xdbc)
  mgemm_k<128,64,6,1,5,1><<<512 + 16, 256, 0, stream>>>(
      XFb, Winv, ycat, NFP_, 0, nullptr, nullptr, nullptr, nullptr, 16, 32,
      NFP_, nullptr, nullptr, xcb, xpwb, xdbc);
  // 5-7. chunked SSM scan -> y_cat[:, :2048] (bf16)
  scan1_k<<<(B_*NCH_*INNER_)/256, 256, 0, stream>>>(xdbc, xconv, A_log, dt_w, dt_b, Pq);
  scan2_k<<<(B_*INNER_*STATE_)/256, 256, 0, stream>>>(Pq);
  scan3_k<<<(B_*NCH_*INNER_)/256, 256, 0, stream>>>(xdbc, xconv, A_log, dt_w, dt_b, Dp, Pq, ycat);
  // 8a. fusion GEMM split-K x2 (2048 x 2048 x 4096), bf16 partials -> fpart
  mgemm_k<128,128,8,0,0,2><<<2*256, 512, 0, stream>>>(
      ycat, fuswb, fpart, 2048, 2048, nullptr, nullptr, nullptr, nullptr, 16, 16,
      4096, nullptr, nullptr, nullptr, nullptr, nullptr);
  // 8b. combine partials + gate epilogue -> ycomb bf16
  combine_gate_k<<<(2048*2048/4)/256, 256, 0, stream>>>(
      fpart, fus_b, ycat, xz, ycomb);
  // 9. out proj split-K x4 (2048 x 1024 x 2048) -> f32 partials in opart
  //    (opart spans xconv..Pq, dead after combine/scan3)
  mgemm_k<64,64,7,1,0,4><<<4*512, 128, 0, stream>>>(
      ycomb, outwb, opart, 512, 1024, nullptr, nullptr, nullptr, nullptr, 16, 32,
      2048, nullptr, nullptr, nullptr, nullptr, nullptr);
  // 10. layernorm over (4 partials + residual) -> d_out
  ln4_k<<<M_, 256, 0, stream>>>(opart, x, ln_g, ln_b, out);
}

// Round 12
// 358.983 us; speedup vs baseline: 1.1116x; 1.0252x over previous
//
#include <hip/hip_runtime.h>
#include <math.h>

#define B_ 2
#define L_ 1024
#define DM_ 1024
#define STATE_ 16
#define CONV_ 4
#define DTR_ 8
#define INNER_ 2048
#define M_ (B_*L_)        /* 2048 rows (b,l) */
#define MD_ (B_*INNER_)   /* 4096 rows (b,c) */
#define NFFT_ 513
#define NFP_ 1088         /* 2*513=1026 padded to 17*64 */
#define NCH_ 32
#define CHL_ 32

typedef unsigned short u16;
typedef __attribute__((ext_vector_type(8))) short short8;
typedef __attribute__((ext_vector_type(8))) __bf16 bf16x8;
typedef __attribute__((ext_vector_type(4))) float f32x4;

__device__ __forceinline__ float frcp_(float x) { return __builtin_amdgcn_rcpf(x); }
__device__ __forceinline__ float fexp_(float x) { return __expf(x); }
__device__ __forceinline__ float fsigm_(float x) { return frcp_(1.f + __expf(-x)); }
__device__ __forceinline__ float fsilu_(float x) { return x * frcp_(1.f + __expf(-x)); }
__device__ __forceinline__ float fsoftplus_(float v) {
  return (v > 20.f) ? v : __logf(1.f + __expf(v));
}
__device__ __forceinline__ u16 f2bf(float f) {
  union { float f; unsigned u; } v; v.f = f;
  unsigned r = v.u + 0x7fffu + ((v.u >> 16) & 1u);
  return (u16)(r >> 16);
}
__device__ __forceinline__ float bf2f(u16 h) {
  union { unsigned u; float f; } v; v.u = ((unsigned)h) << 16;
  return v.f;
}
__device__ __forceinline__ void gload16(const void* g, void* l) {
  __builtin_amdgcn_global_load_lds(
      (const __attribute__((address_space(1))) unsigned*)g,
      (__attribute__((address_space(3))) unsigned*)l, 16, 0, 0);
}
__device__ __forceinline__ f32x4 mfma_bf16(short8 a, short8 b, f32x4 c) {
  return __builtin_amdgcn_mfma_f32_16x16x32_bf16(
      __builtin_bit_cast(bf16x8, a), __builtin_bit_cast(bf16x8, b), c, 0, 0, 0);
}

// ---------------- aux bodies ------------------------------------------------
// 16 contiguous floats per thread -> bf16
__device__ __forceinline__ void cvt16_body(int eb, int nthr, int t,
    const float* __restrict__ src, u16* __restrict__ dst)
{
  int i = (eb*nthr + t)*16;
  #pragma unroll
  for (int q = 0; q < 4; q++) {
    float4 v = *(const float4*)(src + i + q*4);
    ushort4 o;
    o.x = f2bf(v.x); o.y = f2bf(v.y); o.z = f2bf(v.z); o.w = f2bf(v.w);
    *(ushort4*)(dst + i + q*4) = o;
  }
}

// DFT matrix (bf16, K-contiguous): W[col*1024 + l], col < NFP_
__device__ __forceinline__ void genWdft_body(int idx, u16* __restrict__ W)
{
  int l = idx & (L_-1);
  int col = idx >> 10;
  float v = 0.f;
  int f = col >> 1;
  if (f < NFFT_) {
    int ph = (l*f) & (L_-1);
    float th = (float)ph * (6.283185307179586f / (float)L_);
    v = (col & 1) ? -__sinf(th) : __cosf(th);
  }
  W[idx] = f2bf(v);
}

// inverse-DFT matrix: W[l*NFP_ + r], l < 1024, r < NFP_
__device__ __forceinline__ void genWinv_body(int idx, u16* __restrict__ W)
{
  int r = idx % NFP_;
  int l = idx / NFP_;
  int f = r >> 1;
  float v = 0.f;
  if (f < NFFT_) {
    bool edge = (f == 0) || (f == 512);
    float sc = (edge ? 1.f : 2.f) / (float)L_;
    int ph = (f*l) & (L_-1);
    float th = (float)ph * (6.283185307179586f / (float)L_);
    if (r & 1) v = edge ? 0.f : -sc*__sinf(th);
    else       v = sc*__cosf(th);
  }
  W[idx] = f2bf(v);
}

// depthwise causal conv(4) + silu, 8 l per thread, ALL-bf16 path:
// reads xz bf16, emits x_inner^T bf16 (raw copy, no re-round) into
// xt[b*2048+c][l], and writes conv+silu output DIRECTLY as bf16 xcb.
__device__ __forceinline__ void conv_xt_body(int idx, const u16* __restrict__ xzb,
    const float* __restrict__ cw, const float* __restrict__ cb,
    u16* __restrict__ xcb, u16* __restrict__ xt)
{
  int c = idx & (INNER_-1);
  int g = idx >> 11;                        // 0..255
  int b = g >> 7;
  int lb = (g & 127) * 8;
  float w0=cw[c*4+0], w1=cw[c*4+1], w2=cw[c*4+2], w3=cw[c*4+3];
  float bias = cb[c];
  u16 raw[11]; float v[11];
  #pragma unroll
  for (int j = 0; j < 11; j++) {
    int l = lb - 3 + j;
    raw[j] = (l >= 0) ? xzb[((size_t)((b << 10) + l))*4096 + c] : (u16)0;
    v[j] = bf2f(raw[j]);
  }
  union { u16 a[8]; short8 v8; } tu;
  #pragma unroll
  for (int j = 0; j < 8; j++) tu.a[j] = raw[j+3];
  *(short8*)&xt[(((size_t)(b*INNER_ + c)) << 10) + lb] = tu.v8;
  #pragma unroll
  for (int j = 0; j < 8; j++) {
    float s = bias + w0*v[j] + w1*v[j+1] + w2*v[j+2] + w3*v[j+3];
    xcb[((size_t)((b << 10) + lb + j))*INNER_ + c] = f2bf(fsilu_(s));
  }
}

// ---------------- launch 0: cvt x + in_w, genWdft, cvt fus_w (no LDS) -------
#define CVT2_N0 2097152
__global__ __launch_bounds__(256) void cvt3_k(
    const float* __restrict__ s0, const float* __restrict__ s1,
    u16* __restrict__ out, u16* __restrict__ Wd,
    const float* __restrict__ fws, u16* __restrict__ fwd)
{
  int eb = blockIdx.x;
  if (eb < 6144) {
    int i = (eb*256 + threadIdx.x) * 4;
    const float* src; int off;
    if (i < CVT2_N0) { src = s0; off = 0; }
    else             { src = s1; off = CVT2_N0; }
    float4 v = *(const float4*)(src + (i - off));
    ushort4 o;
    o.x = f2bf(v.x); o.y = f2bf(v.y); o.z = f2bf(v.z); o.w = f2bf(v.w);
    *(ushort4*)(out + i) = o;
  } else if (eb < 10496) {
    genWdft_body((eb - 6144)*256 + threadIdx.x, Wd);
  } else {
    cvt16_body(eb - 10496, 256, threadIdx.x, fws, fwd);
  }
}

// ---------------- standalone aux launch: conv+xt, genWinv, cvts -------------
__global__ __launch_bounds__(256) void aux2_k(
    const u16* __restrict__ xzb, const float* __restrict__ cw,
    const float* __restrict__ cb, u16* __restrict__ xcb,
    u16* __restrict__ xt, u16* __restrict__ Winv,
    const float* __restrict__ ows, u16* __restrict__ owd,
    const float* __restrict__ xpws, u16* __restrict__ xpwd)
{
  int eb = blockIdx.x;
  if (eb < 2048)      conv_xt_body(eb*256 + threadIdx.x, xzb, cw, cb, xcb, xt);
  else if (eb < 6400) genWinv_body((eb - 2048)*256 + threadIdx.x, Winv);
  else if (eb < 6912) cvt16_body(eb - 6400, 256, threadIdx.x, ows, owd);
  else                cvt16_body(eb - 6912, 256, threadIdx.x, xpws, xpwd);
}

// ---------------- bf16 MFMA GEMM (templated tile, double-buffered) ----------
// C[m,n] = sum_k A[m,k0+k]*Bt[n,k0+k], k < K (per-split), row stride ldk.
// KS splits along K; split ks = bid/(gx*gy), k0 = ks*K.
// AUX blocks beyond KS*gx*gy:
//   5 = SECOND GEMM (x_dbc): same MFMA body, runtime-overridden operands
//       (A=xga, B=xgb, K=2048, single col-tile), f32 n<40 epilogue into xgc.
//       Requires TM=128, TN=64.
// EPI: 0 plain f32; 3 spectral filter (bf16); 6 inv-DFT via LDS-transpose;
//      7 f32 split-K partial; 8 bf16 C/partial (KS=1 -> plain bf16 C).
// NOTE: operand-override locals named Aop/Bop — "B_" is a macro!
template<int TM, int TN, int EPI, int YCH, int AUX, int KS>
__global__ __launch_bounds__((TM/64)*(TN/32)*64) void mgemm_k(
    const u16* __restrict__ Ab, const u16* __restrict__ Bb,
    void* __restrict__ Cout, int K, int ldc,
    const float* __restrict__ aux0, u16* __restrict__ aux1,
    const float* __restrict__ aux2, const float* __restrict__ aux3,
    int gx, int gy,
    int ldk,
    const u16* __restrict__ xga, const u16* __restrict__ xgb,
    float* __restrict__ xgc)
{
  constexpr int WN   = TN/32;
  constexpr int NW   = (TM/64)*WN;
  constexpr int NTHR = NW*64;
  __shared__ __align__(16) u16 As[2][TM*64];
  __shared__ __align__(16) u16 Bs[2][TN*64];
  const int t = threadIdx.x;
  const int nwg = gx * gy;

  bool xg = false;
  int xgi = 0;
  if constexpr (AUX == 5) {
    int eb = (int)blockIdx.x - nwg*KS;
    if (eb >= 0) { xg = true; xgi = eb; }
  }

  const int lane = t & 63;
  const int w = t >> 6;
  const int wm = w / WN, wn = w % WN;

  // operand setup: main GEMM (split-K + XCD-chunked remap) or xg override
  const u16* Aop = Ab;
  const u16* Bop = Bb;
  int Kr = K, ldkr = ldk, k0 = 0;
  int M0, N0;
  if (xg) {
    Aop = xga; Bop = xgb; Kr = 2048; ldkr = 2048;
    M0 = xgi * TM; N0 = 0;
  } else {
    int bid = blockIdx.x;
    int ks = 0;
    if constexpr (KS > 1) { ks = bid / nwg; bid -= ks*nwg; }
    k0 = ks * K;
    const int lid = (bid & 7) * (nwg >> 3) + (bid >> 3);
    int bx, by;
    if (YCH) { by = lid / gx; bx = lid - by*gx; }
    else     { bx = lid / gy; by = lid - bx*gy; }
    M0 = by * TM; N0 = bx * TN;
    if constexpr (EPI == 7) {
      Cout = (void*)((float*)Cout + (size_t)ks * ((size_t)gy*TM*ldc));
    } else if constexpr (EPI == 8) {
      Cout = (void*)((u16*)Cout + (size_t)ks * ((size_t)gy*TM*ldc));
    }
  }

  f32x4 acc[4][2] = {};

  auto stage = [&](int buf, int kk0) {
    #pragma unroll
    for (int q = 0; q < TM*8/NTHR; q++) {
      int u = q*NTHR + t;
      int row = u >> 3, gpr = u & 7;
      int grp = gpr ^ (row & 7);        // XOR swizzle
      gload16(Aop + (size_t)(M0+row)*ldkr + k0 + kk0 + grp*8, &As[buf][u*8]);
    }
    #pragma unroll
    for (int q = 0; q < TN*8/NTHR; q++) {
      int u = q*NTHR + t;
      int row = u >> 3, gpr = u & 7;
      int grp = gpr ^ (row & 7);
      gload16(Bop + (size_t)(N0+row)*ldkr + k0 + kk0 + grp*8, &Bs[buf][u*8]);
    }
  };

  stage(0, 0);
  const int nk = Kr >> 6;
  for (int kst = 0; kst < nk; kst++) {
    const int buf = kst & 1;
    __syncthreads();                    // drain stage(buf); protect buf^1 overwrite
    if (kst + 1 < nk) stage(buf ^ 1, (kst + 1) << 6);
    const u16* Asb = As[buf];
    const u16* Bsb = Bs[buf];
    #pragma unroll
    for (int kk = 0; kk < 2; kk++) {
      const int quad = lane >> 4;
      const int grp = kk*4 + quad;
      short8 af[4], bfr[2];
      #pragma unroll
      for (int i = 0; i < 4; i++) {
        int row = wm*64 + i*16 + (lane & 15);
        af[i] = *(const short8*)&Asb[(row*8 + (grp ^ (row & 7)))*8];
      }
      #pragma unroll
      for (int j = 0; j < 2; j++) {
        int row = wn*32 + j*16 + (lane & 15);
        bfr[j] = *(const short8*)&Bsb[(row*8 + (grp ^ (row & 7)))*8];
      }
      #pragma unroll
      for (int i = 0; i < 4; i++)
        #pragma unroll
        for (int j = 0; j < 2; j++)
          acc[i][j] = mfma_bf16(af[i], bfr[j], acc[i][j]);
    }
  }

  if (xg) {
    // x_dbc epilogue: f32, n<40 only, row stride 40
    #pragma unroll
    for (int i = 0; i < 4; i++) {
      int mbase = M0 + wm*64 + i*16 + (lane >> 4)*4;
      #pragma unroll
      for (int j = 0; j < 2; j++) {
        int n = wn*32 + j*16 + (lane & 15);
        if (n < 40) {
          #pragma unroll
          for (int r = 0; r < 4; r++)
            xgc[(size_t)(mbase + r)*40 + n] = acc[i][j][r];
        }
      }
    }
    return;
  }

  if constexpr (EPI == 6) {
    // LDS-transpose epilogue: tile [c_loc 128][l_loc 64] -> coalesced 16B
    // stores into ycat[(b,l) row][2048 + c]. Pad 66 breaks bank aliasing.
    u16* T = (u16*)&As[0][0];           // 128*66*2 = 16.9KB <= 32KB As
    __syncthreads();                    // all waves done reading As
    #pragma unroll
    for (int i = 0; i < 4; i++) {
      int cb = wm*64 + i*16 + (lane >> 4)*4;
      #pragma unroll
      for (int j = 0; j < 2; j++) {
        int ll = wn*32 + j*16 + (lane & 15);
        #pragma unroll
        for (int r = 0; r < 4; r++)
          T[(cb + r)*66 + ll] = f2bf(acc[i][j][r]);
      }
    }
    __syncthreads();
    const int b2 = M0 >> 11, c0 = M0 & (INNER_-1);
    u16* yc = (u16*)Cout;
    #pragma unroll
    for (int q = 0; q < (TM*TN/8)/NTHR; q++) {
      int task = q*NTHR + t;
      int cg = task & 15, ll = task >> 4;
      union { u16 a[8]; short8 v8; } tu;
      #pragma unroll
      for (int e = 0; e < 8; e++) tu.a[e] = T[(cg*8 + e)*66 + ll];
      *(short8*)&yc[((size_t)((b2 << 10) + N0 + ll) << 12) + 2048 + c0 + cg*8] = tu.v8;
    }
  } else {
    // C/D layout: col = lane&15, row = (lane>>4)*4 + r
    #pragma unroll
    for (int i = 0; i < 4; i++) {
      int mbase = M0 + wm*64 + i*16 + (lane >> 4)*4;
      #pragma unroll
      for (int j = 0; j < 2; j++) {
        int n = N0 + wn*32 + j*16 + (lane & 15);
        #pragma unroll
        for (int r = 0; r < 4; r++) {
          int m = mbase + r;
          float v = acc[i][j][r];
          if (EPI == 0) {
            ((float*)Cout)[(size_t)m*ldc + n] = v;
          } else if (EPI == 3) {        // spectral filter, complex pair via shfl
            float pv = __shfl_xor(v, 1, 64);
            int f = n >> 1;
            float outv = 0.f;
            if (f < NFFT_) {
              int c = m & (INNER_-1);
              float d  = fexp_(-aux2[c] * (float)f * (1.f/512.f));
              float wr = aux0[c*NFFT_+f]*d, wi = aux3[c*NFFT_+f]*d;
              float a = (n & 1) ? pv : v;
              float b = (n & 1) ? v : pv;
              outv = (n & 1) ? (a*wi + b*wr) : (a*wr - b*wi);
            }
            ((u16*)Cout)[(size_t)m*ldc + n] = f2bf(outv);
          } else if (EPI == 7) {        // f32 split-K partial
            ((float*)Cout)[(size_t)m*ldc + n] = v;
          } else {                      // 8: bf16 C / split-K partial
            ((u16*)Cout)[(size_t)m*ldc + n] = f2bf(v);
          }
        }
      }
    }
  }
}

// ---------------- fusion combine: gate epilogue over bf16 partials ----------
__global__ __launch_bounds__(256) void combine_gate_k(
    const u16* __restrict__ P, const float* __restrict__ fus_b,
    const u16* __restrict__ ycat, const u16* __restrict__ xzb,
    u16* __restrict__ ycomb)
{
  int i4 = (blockIdx.x*256 + threadIdx.x)*4;   // m*2048 + n
  int m = i4 >> 11, n = i4 & 2047;
  ushort4 p0 = *(const ushort4*)(P + i4);
  ushort4 p1 = *(const ushort4*)(P + 4194304 + i4);
  ushort4 ysv = *(const ushort4*)(ycat + (size_t)m*4096 + n);
  ushort4 ypv = *(const ushort4*)(ycat + (size_t)m*4096 + 2048 + n);
  ushort4 zv  = *(const ushort4*)(xzb + (size_t)m*4096 + 2048 + n);
  float4 fb = *(const float4*)(fus_b + n);
  float pp[4] = {bf2f(p0.x)+bf2f(p1.x), bf2f(p0.y)+bf2f(p1.y),
                 bf2f(p0.z)+bf2f(p1.z), bf2f(p0.w)+bf2f(p1.w)};
  float zz[4] = {bf2f(zv.x), bf2f(zv.y), bf2f(zv.z), bf2f(zv.w)};
  float bb[4] = {fb.x, fb.y, fb.z, fb.w};
  u16 ys[4] = {ysv.x, ysv.y, ysv.z, ysv.w};
  u16 yp[4] = {ypv.x, ypv.y, ypv.z, ypv.w};
  ushort4 o;
  u16* op = (u16*)&o;
  #pragma unroll
  for (int j = 0; j < 4; j++) {
    float g = fsigm_(pp[j] + bb[j]);
    op[j] = f2bf((g*bf2f(ys[j]) + (1.f-g)*bf2f(yp[j]))*fsilu_(zz[j]));
  }
  *(ushort4*)(ycomb + i4) = o;
}

// ---------------- SSM chunked scan (prefetched; xconv read as bf16) ---------
__global__ __launch_bounds__(256) void scan1_k(
    const float* __restrict__ xdbc, const u16* __restrict__ xcb,
    const float* __restrict__ A_log, const float* __restrict__ dtw,
    const float* __restrict__ dtb, float* __restrict__ Pq)
{
  int idx = blockIdx.x*256 + threadIdx.x;   // (b*NCH+ch)*INNER + e
  int e  = idx & (INNER_-1);
  int bc = idx >> 11;
  int ch = bc & (NCH_-1);
  int b  = bc >> 5;
  float A[STATE_];
  #pragma unroll
  for (int s=0;s<STATE_;s++) A[s] = -fexp_(A_log[e*STATE_+s]);
  float w[DTR_];
  #pragma unroll
  for (int r=0;r<DTR_;r++) w[r] = dtw[e*DTR_+r];
  float bias = dtb[e];
  float h[STATE_] = {};
  float sdt = 0.f;
  int mbase = b*L_ + ch*CHL_;
  float dtx[DTR_], Bv[STATE_], xcv;
  {
    const float* row = xdbc + (size_t)mbase*40;
    #pragma unroll
    for (int r=0;r<DTR_;r++) dtx[r] = row[r];
    #pragma unroll
    for (int s=0;s<STATE_;s++) Bv[s] = row[8+s];
    xcv = bf2f(xcb[(size_t)mbase*INNER_ + e]);
  }
  for (int l=0;l<CHL_;l++) {
    float ndtx[DTR_], nBv[STATE_], nxcv = 0.f;
    if (l+1 < CHL_) {
      const float* nrow = xdbc + (size_t)(mbase+l+1)*40;
      #pragma unroll
      for (int r=0;r<DTR_;r++) ndtx[r] = nrow[r];
      #pragma unroll
      for (int s=0;s<STATE_;s++) nBv[s] = nrow[8+s];
      nxcv = bf2f(xcb[(size_t)(mbase+l+1)*INNER_ + e]);
    } else {
      #pragma unroll
      for (int r=0;r<DTR_;r++) ndtx[r] = 0.f;
      #pragma unroll
      for (int s=0;s<STATE_;s++) nBv[s] = 0.f;
    }
    float v = bias;
    #pragma unroll
    for (int r=0;r<DTR_;r++) v += dtx[r]*w[r];
    float dt = fsoftplus_(v);
    sdt += dt;
    float dx = dt * xcv;
    #pragma unroll
    for (int s=0;s<STATE_;s++) {
      float dA = fexp_(dt*A[s]);
      h[s] = dA*h[s] + dx*Bv[s];
    }
    #pragma unroll
    for (int r=0;r<DTR_;r++) dtx[r] = ndtx[r];
    #pragma unroll
    for (int s=0;s<STATE_;s++) Bv[s] = nBv[s];
    xcv = nxcv;
  }
  float* o = Pq + (size_t)idx*32;
  #pragma unroll
  for (int s=0;s<STATE_;s++) { o[s] = fexp_(A[s]*sdt); o[16+s] = h[s]; }
}

__global__ __launch_bounds__(256) void scan2_k(float* __restrict__ Pq)
{
  int idx = blockIdx.x*256 + threadIdx.x;   // 65536
  int s = idx & 15;
  int e = (idx >> 4) & (INNER_-1);
  int b = idx >> 15;
  float h = 0.f;
  for (int ch = 0; ch < NCH_; ch++) {
    size_t base = ((size_t)(b*NCH_+ch)*INNER_ + e)*32;
    float p = Pq[base + s];
    float q = Pq[base + 16 + s];
    Pq[base + 16 + s] = h;
    h = p*h + q;
  }
}

__global__ __launch_bounds__(256) void scan3_k(
    const float* __restrict__ xdbc, const u16* __restrict__ xcb,
    const float* __restrict__ A_log, const float* __restrict__ dtw,
    const float* __restrict__ dtb, const float* __restrict__ Dp,
    const float* __restrict__ Pq, u16* __restrict__ ycat)
{
  int idx = blockIdx.x*256 + threadIdx.x;
  int e  = idx & (INNER_-1);
  int bc = idx >> 11;
  int ch = bc & (NCH_-1);
  int b  = bc >> 5;
  float A[STATE_];
  #pragma unroll
  for (int s=0;s<STATE_;s++) A[s] = -fexp_(A_log[e*STATE_+s]);
  float w[DTR_];
  #pragma unroll
  for (int r=0;r<DTR_;r++) w[r] = dtw[e*DTR_+r];
  float bias = dtb[e];
  float Dv = Dp[e];
  float h[STATE_];
  const float* hi = Pq + (size_t)idx*32 + 16;
  #pragma unroll
  for (int s=0;s<STATE_;s++) h[s] = hi[s];
  int mbase = b*L_ + ch*CHL_;
  float dtx[DTR_], Bv[STATE_], Cv[STATE_], xcv;
  {
    const float* row = xdbc + (size_t)mbase*40;
    #pragma unroll
    for (int r=0;r<DTR_;r++) dtx[r] = row[r];
    #pragma unroll
    for (int s=0;s<STATE_;s++) { Bv[s] = row[8+s]; Cv[s] = row[24+s]; }
    xcv = bf2f(xcb[(size_t)mbase*INNER_ + e]);
  }
  for (int l=0;l<CHL_;l++) {
    float ndtx[DTR_], nBv[STATE_], nCv[STATE_], nxcv = 0.f;
    if (l+1 < CHL_) {
      const float* nrow = xdbc + (size_t)(mbase+l+1)*40;
      #pragma unroll
      for (int r=0;r<DTR_;r++) ndtx[r] = nrow[r];
      #pragma unroll
      for (int s=0;s<STATE_;s++) { nBv[s] = nrow[8+s]; nCv[s] = nrow[24+s]; }
      nxcv = bf2f(xcb[(size_t)(mbase+l+1)*INNER_ + e]);
    } else {
      #pragma unroll
      for (int r=0;r<DTR_;r++) ndtx[r] = 0.f;
      #pragma unroll
      for (int s=0;s<STATE_;s++) { nBv[s] = 0.f; nCv[s] = 0.f; }
    }
    float v = bias;
    #pragma unroll
    for (int r=0;r<DTR_;r++) v += dtx[r]*w[r];
    float dt = fsoftplus_(v);
    float dx = dt * xcv;
    float y = 0.f;
    #pragma unroll
    for (int s=0;s<STATE_;s++) {
      float dA = fexp_(dt*A[s]);
      h[s] = dA*h[s] + dx*Bv[s];
      y += h[s]*Cv[s];
    }
    ycat[(size_t)(mbase+l)*4096 + e] = f2bf(y + xcv*Dv);
    #pragma unroll
    for (int r=0;r<DTR_;r++) dtx[r] = ndtx[r];
    #pragma unroll
    for (int s=0;s<STATE_;s++) { Bv[s] = nBv[s]; Cv[s] = nCv[s]; }
    xcv = nxcv;
  }
}

// ---------------- layernorm over 4 out_proj partials + residual -------------
__global__ __launch_bounds__(256) void ln4_k(const float* __restrict__ Q,
    const float* __restrict__ xres,
    const float* __restrict__ gma, const float* __restrict__ bta,
    float* __restrict__ out)
{
  int m = blockIdx.x;
  float s=0.f, s2=0.f;
  float v[4];
  #pragma unroll
  for (int j=0;j<4;j++) {
    int n = threadIdx.x + j*256;
    size_t idx = (size_t)m*DM_ + n;
    v[j] = Q[idx] + Q[2097152 + idx] + Q[2*2097152 + idx] + Q[3*2097152 + idx]
         + xres[idx];
    s += v[j]; s2 += v[j]*v[j];
  }
  #pragma unroll
  for (int off=32; off>=1; off>>=1) {
    s  += __shfl_down(s, off);
    s2 += __shfl_down(s2, off);
  }
  __shared__ float rs[4], rs2[4], stats[2];
  int wid = threadIdx.x >> 6;
  if ((threadIdx.x & 63) == 0) { rs[wid]=s; rs2[wid]=s2; }
  __syncthreads();
  if (threadIdx.x == 0) {
    float ts  = rs[0]+rs[1]+rs[2]+rs[3];
    float ts2 = rs2[0]+rs2[1]+rs2[2]+rs2[3];
    float mu  = ts/(float)DM_;
    float var = ts2/(float)DM_ - mu*mu;
    stats[0] = mu; stats[1] = rsqrtf(var + 1e-5f);
  }
  __syncthreads();
  float mu = stats[0], rstd = stats[1];
  #pragma unroll
  for (int j=0;j<4;j++) {
    int n = threadIdx.x + j*256;
    out[(size_t)m*DM_ + n] = (v[j]-mu)*rstd*gma[n] + bta[n];
  }
}

extern "C" void kernel_launch(void* const* d_in, const int* in_sizes, int n_in,
                              void* d_out, int out_size, void* d_ws, size_t ws_size,
                              hipStream_t stream)
{
  const float* x       = (const float*)d_in[0];
  const float* in_w    = (const float*)d_in[1];
  const float* conv_w  = (const float*)d_in[2];
  const float* conv_b  = (const float*)d_in[3];
  const float* A_log   = (const float*)d_in[4];
  const float* Dp      = (const float*)d_in[5];
  const float* xproj_w = (const float*)d_in[6];
  const float* dt_w    = (const float*)d_in[7];
  const float* dt_b    = (const float*)d_in[8];
  const float* f_re    = (const float*)d_in[9];
  const float* f_im    = (const float*)d_in[10];
  const float* s_dec   = (const float*)d_in[11];
  const float* fus_w   = (const float*)d_in[12];
  const float* fus_b   = (const float*)d_in[13];
  const float* out_w   = (const float*)d_in[14];
  const float* ln_g    = (const float*)d_in[15];
  const float* ln_b    = (const float*)d_in[16];
  float* out = (float*)d_out;

  // ---- workspace carve ----
  // fp32 slots (ws offsets in f32 units):
  //   [0 .. 8388608)      : xzb (bf16, 8.4M u16 = first 4.2M f32);
  //                         later: opart (4 x 2048x1024 f32 = 8.4M f32, full slot)
  //   [8388608 .. 12582912): fpart (bf16, 8.4M u16)   (old xconv slot)
  //   [12582912 .. 12664832): xdbc (81920 f32)
  //   [12664832 .. 16859136): Pq (4.2M f32)
  float* ws    = (float*)d_ws;
  u16* xzb     = (u16*)ws;                 // M x 4096 bf16 (xz)
  float* opart = ws;                       // reuse after combine (xzb dead)
  u16* fpart   = (u16*)(ws + 8388608);     // fusion bf16 partials
  float* xdbc  = ws + 8388608 + 4194304;
  float* Pq    = xdbc + 81920;
  u16* ub      = (u16*)(Pq + 4194304);
  u16* xb      = ub;                       // 2097152  x bf16; reused: Winv + xpwb
  u16* inwb    = xb    + 2097152;          // 4194304  in_w bf16; reused as xcb
  u16* fuswb   = inwb  + 4194304;          // 8388608  fus_w bf16 (cvt3 aux)
  u16* outwb   = fuswb + 8388608;          // 2097152  out_w bf16 (aux2)
  u16* xt      = outwb + 2097152;          // 4194304  x_inner^T bf16; reused as ycomb
  u16* Wb      = xt    + 4194304;          // 1114112  Wdft (NFP_ x 1024)
  u16* XFb     = Wb    + 1114112;          // 4456448  (MD x NFP_) bf16
  u16* ycat    = XFb   + 4456448;          // 8388608  (M x 4096) bf16
  u16* ycomb   = xt;
  u16* Winv    = xb;                       // xb dead after L1
  u16* xpwb    = xb + 1114112;             // 40x2048 cvt'd; pad rows 40-63 read
                                           // leftover finite x-bf16 (no NaN)
  u16* xcb     = inwb;                     // conv+silu bf16 (inwb dead after L1)

  // 0. cvt x+in_w (6144) + genWdft (4352) + cvt fus_w (2048) — no-LDS launch
  cvt3_k<<<12544, 256, 0, stream>>>(x, in_w, xb, Wb, fus_w, fuswb);

  // 1. xz = x @ in_proj_w^T (2048 x 4096 x 1024) -> BF16 xzb (EPI=8, KS=1)
  mgemm_k<128,128,8,0,0,1><<<512, 512, 0, stream>>>(
      xb, inwb, xzb, 1024, 4096, nullptr, nullptr, nullptr, nullptr, 32, 16,
      1024, nullptr, nullptr, nullptr);
  // 2. conv+silu -> xcb bf16 + x_inner^T emit (xt) + genWinv + cvt out_w + cvt xproj_w
  aux2_k<<<6932, 256, 0, stream>>>(xzb, conv_w, conv_b, xcb, xt, Winv,
                                   out_w, outwb, xproj_w, xpwb);
  // 3. forward DFT + spectral filter: XFb = filt(xt @ Wdft)  [544 blocks]
  mgemm_k<128,64,3,1,0,1><<<544, 256, 0, stream>>>(
      xt, Wb, XFb, 1024, NFP_, f_re, nullptr, s_dec, f_im, 17, 32,
      1024, nullptr, nullptr, nullptr);
  // 4. inverse DFT (4096 x 1024 x NFP_), LDS-transpose epilogue -> ycat[:,2048:]
  //    [512 GEMM blocks] + x_dbc sub-GEMM (16 blocks: xcb @ xpwb^T -> xdbc)
  mgemm_k<128,64,6,1,5,1><<<512 + 16, 256, 0, stream>>>(
      XFb, Winv, ycat, NFP_, 0, nullptr, nullptr, nullptr, nullptr, 16, 32,
      NFP_, xcb, xpwb, xdbc);
  // 5-7. chunked SSM scan -> y_cat[:, :2048] (bf16)
  scan1_k<<<(B_*NCH_*INNER_)/256, 256, 0, stream>>>(xdbc, xcb, A_log, dt_w, dt_b, Pq);
  scan2_k<<<(B_*INNER_*STATE_)/256, 256, 0, stream>>>(Pq);
  scan3_k<<<(B_*NCH_*INNER_)/256, 256, 0, stream>>>(xdbc, xcb, A_log, dt_w, dt_b, Dp, Pq, ycat);
  // 8a. fusion GEMM split-K x2 (2048 x 2048 x 4096), bf16 partials -> fpart
  mgemm_k<128,128,8,0,0,2><<<2*256, 512, 0, stream>>>(
      ycat, fuswb, fpart, 2048, 2048, nullptr, nullptr, nullptr, nullptr, 16, 16,
      4096, nullptr, nullptr, nullptr);
  // 8b. combine partials + gate epilogue (z read bf16) -> ycomb bf16
  combine_gate_k<<<(2048*2048/4)/256, 256, 0, stream>>>(
      fpart, fus_b, ycat, xzb, ycomb);
  // 9. out proj split-K x4 (2048 x 1024 x 2048) -> f32 partials in opart
  //    (opart = xz slot; xzb dead after combine)
  mgemm_k<64,64,7,1,0,4><<<4*512, 128, 0, stream>>>(
      ycomb, outwb, opart, 512, 1024, nullptr, nullptr, nullptr, nullptr, 16, 32,
      2048, nullptr, nullptr, nullptr);
  // 10. layernorm over (4 partials + residual) -> d_out
  ln4_k<<<M_, 256, 0, stream>>>(opart, x, ln_g, ln_b, out);
}